// Round 1
// baseline (3500.909 us; speedup 1.0000x reference)
//
#include <hip/hip_runtime.h>
#include <math.h>

// ============================================================================
// SBDD point-cloud network, fp32, bs=8, N_PTS=4096, NB=20, S=1.
// Pipeline: knn -> conv_surface -> conv_layer -> gathermax -> pool1 -> knn ->
// conv_layer x2 -> gathermax -> pool2 -> knn -> conv_layer -> {GeM, NetVLAD}.
// ============================================================================

#define NB_K 20
#define BN_EPS 1e-5f

// ---------------------------------------------------------------------------
// Host-side reproduction of np.random.RandomState(seed).permutation(n)
// (legacy MT19937 + random_interval masked rejection + reverse Fisher-Yates)
// ---------------------------------------------------------------------------
namespace {
struct MT19937H {
  unsigned mt[624]; int pos;
  void seed(unsigned s) {
    for (int i = 0; i < 624; i++) { mt[i] = s; s = 1812433253u * (s ^ (s >> 30)) + (unsigned)i + 1u; }
    pos = 624;
  }
  unsigned next() {
    if (pos >= 624) {
      for (int i = 0; i < 624; i++) {
        unsigned y = (mt[i] & 0x80000000u) | (mt[(i + 1) % 624] & 0x7fffffffu);
        unsigned v = mt[(i + 397) % 624] ^ (y >> 1);
        if (y & 1u) v ^= 0x9908b0dfu;
        mt[i] = v;
      }
      pos = 0;
    }
    unsigned y = mt[pos++];
    y ^= y >> 11; y ^= (y << 7) & 0x9d2c5680u; y ^= (y << 15) & 0xefc60000u; y ^= y >> 18;
    return y;
  }
  unsigned interval(unsigned mx) {
    if (mx == 0) return 0;
    unsigned mask = mx;
    mask |= mask >> 1; mask |= mask >> 2; mask |= mask >> 4; mask |= mask >> 8; mask |= mask >> 16;
    unsigned v;
    do { v = next() & mask; } while (v > mx);
    return v;
  }
};
struct Pools {
  int p1[1024];
  int p2[256];
  int arr[4096];
  Pools() {
    MT19937H m;
    m.seed(1);
    for (int i = 0; i < 4096; i++) arr[i] = i;
    for (int i = 4095; i >= 1; i--) {
      int j = (int)m.interval((unsigned)i);
      int t = arr[j]; arr[j] = arr[i]; arr[i] = t;
    }
    for (int i = 0; i < 1024; i++) p1[i] = arr[i];
    m.seed(2);
    for (int i = 0; i < 1024; i++) arr[i] = i;
    for (int i = 1023; i >= 1; i--) {
      int j = (int)m.interval((unsigned)i);
      int t = arr[j]; arr[j] = arr[i]; arr[i] = t;
    }
    for (int i = 0; i < 256; i++) p2[i] = arr[i];
  }
};
Pools g_pools;  // built once at .so load; hipMemcpyAsync'd each launch
}

// ---------------------------------------------------------------------------
// Workspace layout (bytes). Total 52 MB.
// ---------------------------------------------------------------------------
#define OFF_POOL1   (0u)
#define OFF_POOL2   (16u << 10)
#define OFF_DIRN0   (32u << 10)
#define OFF_DIRN1   (36u << 10)
#define OFF_DIRN2   (40u << 10)
#define OFF_DIRN3   (48u << 10)
#define OFF_DIRN4   (56u << 10)
#define OFF_V2      (128u << 10)
#define OFF_V3      (256u << 10)
#define OFF_BN1M    (288u << 10)
#define OFF_BN1R    (292u << 10)
#define OFF_ASUM    (296u << 10)
#define OFF_SCALE1  (304u << 10)
#define OFF_SCALE2  (312u << 10)
#define OFF_HID     (320u << 10)
#define OFF_VLADBN  (352u << 10)
#define OFF_GAT     (384u << 10)
#define OFF_NB      (1u << 20)          // 2.5 MB (neighbor idx, reused all stages)
#define OFF_X1      (4u << 20)          // 16 MB
#define OFF_X2      (20u << 20)         // 16 MB
#define OFF_X3      (36u << 20)         // 8 MB
#define OFF_X4      (44u << 20)         // 8 MB
#define OFF_ACT0    (OFF_X1)
#define OFF_ACT     (OFF_X1 + (1u << 20))
#define OFF_VLAD    (OFF_X1 + (2u << 20))
#define OFF_PART    (OFF_X1 + (8u << 20))  // 128*8*1024 f = 4 MB

// ---------------------------------------------------------------------------
// dir normalization: l2norm(dirs, axis=0) for all 5 dir matrices, one kernel
// ---------------------------------------------------------------------------
__global__ void k_dirnorm(const float* __restrict__ d0, const float* __restrict__ d1,
                          const float* __restrict__ d2, const float* __restrict__ d3,
                          const float* __restrict__ d4,
                          float* __restrict__ o0, float* __restrict__ o1,
                          float* __restrict__ o2, float* __restrict__ o3,
                          float* __restrict__ o4) {
  int i = blockIdx.x * 256 + threadIdx.x;
  const float* src; float* dst; int F, c;
  if      (i < 32)   { src = d0; dst = o0; F = 32;   c = i; }
  else if (i < 96)   { src = d1; dst = o1; F = 64;   c = i - 32; }
  else if (i < 224)  { src = d2; dst = o2; F = 128;  c = i - 96; }
  else if (i < 480)  { src = d3; dst = o3; F = 256;  c = i - 224; }
  else if (i < 1504) { src = d4; dst = o4; F = 1024; c = i - 480; }
  else return;
  float a = src[c], b = src[F + c], cc = src[2 * F + c];
  float nr = sqrtf((a * a + b * b) + cc * cc);
  float inv = 1.0f / fmaxf(nr, 1e-12f);
  dst[c] = a * inv; dst[F + c] = b * inv; dst[2 * F + c] = cc * inv;
}

// ---------------------------------------------------------------------------
// kNN: thread per query, top-21 sorted insertion (stable ties = lower idx 1st)
// ---------------------------------------------------------------------------
template <int N>
__global__ void k_knn(const float* __restrict__ v, int* __restrict__ nb) {
  __shared__ float4 cand[256];
  int q = blockIdx.x * 64 + threadIdx.x;
  int b = blockIdx.y;
  const float* vb = v + (size_t)b * N * 3;
  float xq = vb[q * 3 + 0], yq = vb[q * 3 + 1], zq = vb[q * 3 + 2];
  float sqq = (xq * xq + yq * yq) + zq * zq;
  float kd[21]; int ki[21];
#pragma unroll
  for (int t = 0; t < 21; t++) { kd[t] = 3.4e38f; ki[t] = 0; }
  for (int base = 0; base < N; base += 256) {
    __syncthreads();
    for (int j = threadIdx.x; j < 256; j += 64) {
      int g = base + j;
      float x = vb[g * 3 + 0], y = vb[g * 3 + 1], z = vb[g * 3 + 2];
      cand[j] = make_float4(x, y, z, (x * x + y * y) + z * z);
    }
    __syncthreads();
    for (int j = 0; j < 256; j++) {
      float4 c = cand[j];
      float dot = xq * c.x + yq * c.y + zq * c.z;
      float dist = (sqq + c.w) - 2.0f * dot;
      if (dist < kd[20]) {
        int cidx = base + j;
#pragma unroll
        for (int t = 20; t >= 1; t--) {
          bool shift = dist < kd[t - 1];
          float nk = shift ? kd[t - 1] : dist;
          int   ni = shift ? ki[t - 1] : cidx;
          bool upd = dist < kd[t];
          if (upd) { kd[t] = nk; ki[t] = ni; }
        }
        if (dist < kd[0]) { kd[0] = dist; ki[0] = cidx; }
      }
    }
  }
  int* nbq = nb + ((size_t)b * N + q) * NB_K;
#pragma unroll
  for (int t = 0; t < NB_K; t++) nbq[t] = ki[t + 1];  // drop self
}

// ---------------------------------------------------------------------------
// conv_surface: fm[b,n,f] = max_k relu(dot(normalize(v_nb - v), dirn0[:,f]))
// ---------------------------------------------------------------------------
__global__ void k_surface(const float* __restrict__ v, const int* __restrict__ nb,
                          const float* __restrict__ dirn, float* __restrict__ out) {
  int idx = blockIdx.x * 64 + threadIdx.x;  // b*4096+n
  int b = idx >> 12, n = idx & 4095;
  const float* vb = v + (size_t)b * 4096 * 3;
  float xq = vb[n * 3 + 0], yq = vb[n * 3 + 1], zq = vb[n * 3 + 2];
  float mx[32];
#pragma unroll
  for (int f = 0; f < 32; f++) mx[f] = 0.0f;  // theta >= 0
  for (int k = 0; k < NB_K; k++) {
    int j = nb[(size_t)idx * NB_K + k];
    float dx = vb[j * 3 + 0] - xq, dy = vb[j * 3 + 1] - yq, dz = vb[j * 3 + 2] - zq;
    float nr = sqrtf((dx * dx + dy * dy) + dz * dz);
    float inv = 1.0f / fmaxf(nr, 1e-12f);
    dx *= inv; dy *= inv; dz *= inv;
#pragma unroll
    for (int f = 0; f < 32; f++) {
      float th = dx * dirn[f] + dy * dirn[32 + f] + dz * dirn[64 + f];
      th = fmaxf(th, 0.0f);
      mx[f] = fmaxf(mx[f], th);
    }
  }
#pragma unroll
  for (int f = 0; f < 32; f++) out[(size_t)idx * 32 + f] = mx[f];
}

// ---------------------------------------------------------------------------
// generic GEMM: out[r,c] = sum_k A[r,k]*W[k,c] (+ bias[c])
// ---------------------------------------------------------------------------
__global__ void k_gemm(const float* __restrict__ A, const float* __restrict__ W,
                       const float* __restrict__ bias, float* __restrict__ out,
                       int R, int K, int C) {
  int idx = blockIdx.x * 256 + threadIdx.x;
  if (idx >= R * C) return;
  int r = idx / C, c = idx - r * C;
  const float* a = A + (size_t)r * K;
  float acc = bias ? bias[c] : 0.0f;
  for (int k = 0; k < K; k++) acc += a[k] * W[(size_t)k * C + c];
  out[(size_t)r * C + c] = acc;
}

// ---------------------------------------------------------------------------
// conv_layer combine: out = fc + max_k(relu(d_k . dir_c) * fs_k)  [optional relu]
// ---------------------------------------------------------------------------
template <int COUT, int CPT, bool RELU>
__global__ void k_combine(const float* __restrict__ v, const int* __restrict__ nb,
                          const float* __restrict__ fo, const float* __restrict__ dirn,
                          float* __restrict__ out, int N) {
  constexpr int THREADS = COUT / CPT;
  int bn = blockIdx.x;
  int b = bn / N, n = bn - b * N;
  __shared__ float ds[NB_K][3];
  __shared__ int nbs[NB_K];
  const float* vb = v + (size_t)b * N * 3;
  if (threadIdx.x < NB_K) {
    int j = nb[(size_t)bn * NB_K + threadIdx.x];
    nbs[threadIdx.x] = j;
    float xq = vb[n * 3 + 0], yq = vb[n * 3 + 1], zq = vb[n * 3 + 2];
    float dx = vb[j * 3 + 0] - xq, dy = vb[j * 3 + 1] - yq, dz = vb[j * 3 + 2] - zq;
    float nr = sqrtf((dx * dx + dy * dy) + dz * dz);
    float inv = 1.0f / fmaxf(nr, 1e-12f);
    ds[threadIdx.x][0] = dx * inv;
    ds[threadIdx.x][1] = dy * inv;
    ds[threadIdx.x][2] = dz * inv;
  }
  __syncthreads();
#pragma unroll
  for (int cc = 0; cc < CPT; cc++) {
    int c = threadIdx.x + cc * THREADS;
    float w0 = dirn[c], w1 = dirn[COUT + c], w2 = dirn[2 * COUT + c];
    float acc = -3.4e38f;
    for (int k = 0; k < NB_K; k++) {
      float th = ds[k][0] * w0 + ds[k][1] * w1 + ds[k][2] * w2;
      th = fmaxf(th, 0.0f);
      float fs = fo[((size_t)b * N + nbs[k]) * (2 * COUT) + COUT + c];
      acc = fmaxf(acc, th * fs);
    }
    float res = fo[(size_t)bn * (2 * COUT) + c] + acc;
    if (RELU) res = fmaxf(res, 0.0f);
    out[(size_t)bn * COUT + c] = res;
  }
}

// ---------------------------------------------------------------------------
// gather-max pooling over neighbors: out[b,n,c] = max_k fm[b, nb[k], c]
// ---------------------------------------------------------------------------
template <int C>
__global__ void k_gathermax(const float* __restrict__ fm, const int* __restrict__ nb,
                            float* __restrict__ out, int N) {
  int bn = blockIdx.x;
  int b = bn / N;
  __shared__ int nbs[NB_K];
  if (threadIdx.x < NB_K) nbs[threadIdx.x] = nb[(size_t)bn * NB_K + threadIdx.x];
  __syncthreads();
  int c = threadIdx.x;
  float acc = -3.4e38f;
  for (int k = 0; k < NB_K; k++)
    acc = fmaxf(acc, fm[((size_t)b * N + nbs[k]) * C + c]);
  out[(size_t)bn * C + c] = acc;
}

// ---------------------------------------------------------------------------
// pool-index gather: out[b,i,c] = in[b, pool[i], c]
// ---------------------------------------------------------------------------
__global__ void k_poolgather(const float* __restrict__ in, const int* __restrict__ pool,
                             float* __restrict__ out, int n_in, int n_out, int C) {
  int idx = blockIdx.x * 256 + threadIdx.x;
  if (idx >= 8 * n_out * C) return;
  int c = idx % C; int t = idx / C; int i = t % n_out; int b = t / n_out;
  out[idx] = in[((size_t)b * n_in + pool[i]) * C + c];
}

// ---------------------------------------------------------------------------
// GeM pooling: y[b,f] = (mean_n max(fm4[b,n,f],1e-6)^p)^(1/p)
// ---------------------------------------------------------------------------
__global__ void k_gem(const float* __restrict__ fm4, const float* __restrict__ gp,
                      float* __restrict__ y) {
  int idx = blockIdx.x * 256 + threadIdx.x;  // b*1024+f
  int b = idx >> 10, f = idx & 1023;
  float p = gp[0];
  float s = 0.0f;
  for (int n = 0; n < 256; n++) {
    float val = fmaxf(fm4[((size_t)b * 256 + n) * 1024 + f], 1e-6f);
    s += powf(val, p);
  }
  y[idx] = powf(s * (1.0f / 256.0f), 1.0f / p);
}

// ---------------------------------------------------------------------------
// NetVLAD pieces
// ---------------------------------------------------------------------------
__global__ void k_bnstats(const float* __restrict__ x, int R, int C,
                          float* __restrict__ mean, float* __restrict__ rstd) {
  int c = blockIdx.x;
  __shared__ float red[256];
  float s = 0.0f;
  for (int r = threadIdx.x; r < R; r += 256) s += x[(size_t)r * C + c];
  red[threadIdx.x] = s; __syncthreads();
  for (int st = 128; st > 0; st >>= 1) {
    if (threadIdx.x < st) red[threadIdx.x] += red[threadIdx.x + st];
    __syncthreads();
  }
  float m = red[0] / (float)R;
  __syncthreads();
  float s2 = 0.0f;
  for (int r = threadIdx.x; r < R; r += 256) {
    float d = x[(size_t)r * C + c] - m; s2 += d * d;
  }
  red[threadIdx.x] = s2; __syncthreads();
  for (int st = 128; st > 0; st >>= 1) {
    if (threadIdx.x < st) red[threadIdx.x] += red[threadIdx.x + st];
    __syncthreads();
  }
  if (threadIdx.x == 0) {
    mean[c] = m;
    rstd[c] = 1.0f / sqrtf(red[0] / (float)R + BN_EPS);
  }
}

// BN-apply + row softmax over 64 cols (one wave per row)
__global__ void k_softmax(const float* __restrict__ a0, const float* __restrict__ mean,
                          const float* __restrict__ rstd, const float* __restrict__ g,
                          const float* __restrict__ bb, float* __restrict__ act) {
  int r = blockIdx.x, c = threadIdx.x;
  float x = (a0[(size_t)r * 64 + c] - mean[c]) * rstd[c] * g[c] + bb[c];
  float mx = x;
  for (int off = 32; off > 0; off >>= 1) mx = fmaxf(mx, __shfl_xor(mx, off));
  float e = expf(x - mx);
  float sm = e;
  for (int off = 32; off > 0; off >>= 1) sm += __shfl_xor(sm, off);
  act[(size_t)r * 64 + c] = e / sm;
}

__global__ void k_colsum(const float* __restrict__ act, float* __restrict__ asum) {
  int b = blockIdx.x, k = threadIdx.x;
  float s = 0.0f;
  for (int m = 0; m < 256; m++) s += act[((size_t)b * 256 + m) * 64 + k];
  asum[b * 64 + k] = s;
}

// vlad[b,f,k] = sum_m act[b,m,k]*xv[b,m,f] - asum[b,k]*cw2[f,k]
__global__ void k_vlad(const float* __restrict__ act, const float* __restrict__ xv,
                       const float* __restrict__ asum, const float* __restrict__ cw2,
                       float* __restrict__ vlad) {
  int bf = blockIdx.x;              // b*1024+f
  int b = bf >> 10, f = bf & 1023;
  __shared__ float xs[256];
  for (int m = threadIdx.x; m < 256; m += 64)
    xs[m] = xv[((size_t)b * 256 + m) * 1024 + f];
  __syncthreads();
  int k = threadIdx.x;
  float acc = 0.0f;
  for (int m = 0; m < 256; m++) acc += act[((size_t)b * 256 + m) * 64 + k] * xs[m];
  vlad[(size_t)bf * 64 + k] = acc - asum[b * 64 + k] * cw2[f * 64 + k];
}

__global__ void k_norm1(const float* __restrict__ vlad, float* __restrict__ scale1) {
  int bk = blockIdx.x;  // b*64+k
  int b = bk >> 6, k = bk & 63;
  float s = 0.0f;
  for (int f = threadIdx.x; f < 1024; f += 64) {
    float val = vlad[((size_t)b * 1024 + f) * 64 + k];
    s += val * val;
  }
  for (int off = 32; off > 0; off >>= 1) s += __shfl_xor(s, off);
  if (threadIdx.x == 0) scale1[bk] = 1.0f / fmaxf(sqrtf(s), 1e-12f);
}

__global__ void k_norm2(const float* __restrict__ vlad, const float* __restrict__ scale1,
                        float* __restrict__ scale2) {
  int b = blockIdx.x;
  __shared__ float red[256];
  float s = 0.0f;
  for (int i = threadIdx.x; i < 65536; i += 256) {
    float val = vlad[(size_t)b * 65536 + i] * scale1[b * 64 + (i & 63)];
    s += val * val;
  }
  red[threadIdx.x] = s; __syncthreads();
  for (int st = 128; st > 0; st >>= 1) {
    if (threadIdx.x < st) red[threadIdx.x] += red[threadIdx.x + st];
    __syncthreads();
  }
  if (threadIdx.x == 0) scale2[b] = 1.0f / fmaxf(sqrtf(red[0]), 1e-12f);
}

__global__ void k_vscale(float* __restrict__ vlad, const float* __restrict__ scale1,
                         const float* __restrict__ scale2) {
  int idx = blockIdx.x * 256 + threadIdx.x;  // < 8*65536
  int b = idx >> 16; int r = idx & 65535;
  vlad[idx] = vlad[idx] * scale1[b * 64 + (r & 63)] * scale2[b];
}

// split-K hidden GEMM: partial[kb,b,col] = sum_{k in chunk} vlad[b,k]*hw[k,col]
__global__ void k_hidden_partial(const float* __restrict__ vlad, const float* __restrict__ hw,
                                 float* __restrict__ partial) {
  __shared__ float vs[8][512];
  int cg = blockIdx.x;   // 0..3
  int kb = blockIdx.y;   // 0..127
  int col = cg * 256 + threadIdx.x;
  int k0 = kb * 512;
  for (int i = threadIdx.x; i < 8 * 512; i += 256) {
    int b = i >> 9, k = i & 511;
    vs[b][k] = vlad[(size_t)b * 65536 + k0 + k];
  }
  __syncthreads();
  float acc[8] = {0, 0, 0, 0, 0, 0, 0, 0};
  for (int k = 0; k < 512; k++) {
    float w = hw[(size_t)(k0 + k) * 1024 + col];
#pragma unroll
    for (int b = 0; b < 8; b++) acc[b] += vs[b][k] * w;
  }
#pragma unroll
  for (int b = 0; b < 8; b++)
    partial[((size_t)kb * 8 + b) * 1024 + col] = acc[b];
}

__global__ void k_hidden_reduce(const float* __restrict__ partial, float* __restrict__ hid) {
  int idx = blockIdx.x * 256 + threadIdx.x;  // b*1024+c
  int b = idx >> 10, c = idx & 1023;
  float s = 0.0f;
  for (int kb = 0; kb < 128; kb++) s += partial[((size_t)kb * 8 + b) * 1024 + c];
  hid[idx] = s;
}

__global__ void k_bn8(const float* __restrict__ x, const float* __restrict__ g,
                      const float* __restrict__ bb, float* __restrict__ out) {
  int c = blockIdx.x * 256 + threadIdx.x;
  if (c >= 1024) return;
  float v[8]; float s = 0.0f;
#pragma unroll
  for (int b = 0; b < 8; b++) { v[b] = x[b * 1024 + c]; s += v[b]; }
  float m = s * 0.125f; float s2 = 0.0f;
#pragma unroll
  for (int b = 0; b < 8; b++) { float d = v[b] - m; s2 += d * d; }
  float rstd = 1.0f / sqrtf(s2 * 0.125f + BN_EPS);
#pragma unroll
  for (int b = 0; b < 8; b++) out[b * 1024 + c] = (v[b] - m) * rstd * g[c] + bb[c];
}

// gating BN + sigmoid + multiply -> desc
__global__ void k_gbn_out(const float* __restrict__ gat, const float* __restrict__ g,
                          const float* __restrict__ bb, const float* __restrict__ vladbn,
                          float* __restrict__ desc) {
  int c = blockIdx.x * 256 + threadIdx.x;
  if (c >= 1024) return;
  float v[8]; float s = 0.0f;
#pragma unroll
  for (int b = 0; b < 8; b++) { v[b] = gat[b * 1024 + c]; s += v[b]; }
  float m = s * 0.125f; float s2 = 0.0f;
#pragma unroll
  for (int b = 0; b < 8; b++) { float d = v[b] - m; s2 += d * d; }
  float rstd = 1.0f / sqrtf(s2 * 0.125f + BN_EPS);
#pragma unroll
  for (int b = 0; b < 8; b++) {
    float x = (v[b] - m) * rstd * g[c] + bb[c];
    float gate = 1.0f / (1.0f + expf(-x));
    desc[b * 1024 + c] = vladbn[b * 1024 + c] * gate;
  }
}

// ---------------------------------------------------------------------------
// launch
// ---------------------------------------------------------------------------
extern "C" void kernel_launch(void* const* d_in, const int* in_sizes, int n_in,
                              void* d_out, int out_size, void* d_ws, size_t ws_size,
                              hipStream_t stream) {
  (void)in_sizes; (void)n_in; (void)out_size; (void)ws_size;
  const float* x    = (const float*)d_in[0];
  const float* dir0 = (const float*)d_in[1];
  const float* W1   = (const float*)d_in[2];
  const float* b1   = (const float*)d_in[3];
  const float* dir1 = (const float*)d_in[4];
  const float* W2   = (const float*)d_in[5];
  const float* b2   = (const float*)d_in[6];
  const float* dir2 = (const float*)d_in[7];
  const float* W3   = (const float*)d_in[8];
  const float* b3   = (const float*)d_in[9];
  const float* dir3 = (const float*)d_in[10];
  const float* W4   = (const float*)d_in[11];
  const float* b4   = (const float*)d_in[12];
  const float* dir4 = (const float*)d_in[13];
  const float* gemp = (const float*)d_in[14];
  const float* cw   = (const float*)d_in[15];
  const float* cw2  = (const float*)d_in[16];
  const float* hw   = (const float*)d_in[17];
  const float* bn1g = (const float*)d_in[18];
  const float* bn1b = (const float*)d_in[19];
  const float* bn2g = (const float*)d_in[20];
  const float* bn2b = (const float*)d_in[21];
  const float* gw   = (const float*)d_in[22];
  const float* gbng = (const float*)d_in[23];
  const float* gbnb = (const float*)d_in[24];
  float* out = (float*)d_out;
  char* ws = (char*)d_ws;

  float* F_DIRN0 = (float*)(ws + OFF_DIRN0);
  float* F_DIRN1 = (float*)(ws + OFF_DIRN1);
  float* F_DIRN2 = (float*)(ws + OFF_DIRN2);
  float* F_DIRN3 = (float*)(ws + OFF_DIRN3);
  float* F_DIRN4 = (float*)(ws + OFF_DIRN4);
  int*   I_POOL1 = (int*)(ws + OFF_POOL1);
  int*   I_POOL2 = (int*)(ws + OFF_POOL2);
  int*   I_NB    = (int*)(ws + OFF_NB);
  float* F_V2    = (float*)(ws + OFF_V2);
  float* F_V3    = (float*)(ws + OFF_V3);
  float* F_X1    = (float*)(ws + OFF_X1);
  float* F_X2    = (float*)(ws + OFF_X2);
  float* F_X3    = (float*)(ws + OFF_X3);
  float* F_X4    = (float*)(ws + OFF_X4);

  // POOL constants (host-precomputed numpy RandomState permutations)
  hipMemcpyAsync(I_POOL1, g_pools.p1, sizeof(g_pools.p1), hipMemcpyHostToDevice, stream);
  hipMemcpyAsync(I_POOL2, g_pools.p2, sizeof(g_pools.p2), hipMemcpyHostToDevice, stream);

  k_dirnorm<<<6, 256, 0, stream>>>(dir0, dir1, dir2, dir3, dir4,
                                   F_DIRN0, F_DIRN1, F_DIRN2, F_DIRN3, F_DIRN4);

  // ---- level 0: 4096 pts ----
  k_knn<4096><<<dim3(64, 8), 64, 0, stream>>>(x, I_NB);
  k_surface<<<512, 64, 0, stream>>>(x, I_NB, F_DIRN0, F_X3);                 // fm1 (32ch)
  k_gemm<<<(32768 * 128) / 256, 256, 0, stream>>>(F_X3, W1, b1, F_X1, 32768, 32, 128);  // fo1
  k_combine<64, 1, true><<<32768, 64, 0, stream>>>(x, I_NB, F_X1, F_DIRN1, F_X4, 4096); // fm2 (64ch)
  k_gathermax<64><<<32768, 64, 0, stream>>>(F_X4, I_NB, F_X2, 4096);         // fm2m
  // pool1 -> 1024 pts
  k_poolgather<<<(8 * 1024 * 3 + 255) / 256, 256, 0, stream>>>(x, I_POOL1, F_V2, 4096, 1024, 3);
  k_poolgather<<<(8 * 1024 * 64 + 255) / 256, 256, 0, stream>>>(F_X2, I_POOL1, F_X3, 4096, 1024, 64); // fm2p

  // ---- level 1: 1024 pts ----
  k_knn<1024><<<dim3(16, 8), 64, 0, stream>>>(F_V2, I_NB);
  k_gemm<<<(8192 * 256) / 256, 256, 0, stream>>>(F_X3, W2, b2, F_X4, 8192, 64, 256);    // fo2
  k_combine<128, 1, true><<<8192, 128, 0, stream>>>(F_V2, I_NB, F_X4, F_DIRN2, F_X1, 1024); // fm3 (128ch)
  k_gemm<<<(8192 * 512) / 256, 256, 0, stream>>>(F_X1, W3, b3, F_X2, 8192, 128, 512);   // fo3
  k_combine<256, 1, true><<<8192, 256, 0, stream>>>(F_V2, I_NB, F_X2, F_DIRN3, F_X4, 1024); // fm4a (256ch)
  k_gathermax<256><<<8192, 256, 0, stream>>>(F_X4, I_NB, F_X1, 1024);        // fm4m
  // pool2 -> 256 pts
  k_poolgather<<<(8 * 256 * 3 + 255) / 256, 256, 0, stream>>>(F_V2, I_POOL2, F_V3, 1024, 256, 3);
  k_poolgather<<<(8 * 256 * 256 + 255) / 256, 256, 0, stream>>>(F_X1, I_POOL2, F_X3, 1024, 256, 256); // fm4p

  // ---- level 2: 256 pts ----
  k_knn<256><<<dim3(4, 8), 64, 0, stream>>>(F_V3, I_NB);
  k_gemm<<<(2048 * 2048) / 256, 256, 0, stream>>>(F_X3, W4, b4, F_X2, 2048, 256, 2048); // fo4
  k_combine<1024, 4, false><<<2048, 256, 0, stream>>>(F_V3, I_NB, F_X2, F_DIRN4, F_X4, 256); // fm4 (1024ch)

  // ---- GeM head -> out[0:8192] ----
  k_gem<<<32, 256, 0, stream>>>(F_X4, gemp, out);

  // ---- NetVLAD head -> out[8192:16384] ----
  float* F_ACT0 = (float*)(ws + OFF_ACT0);
  float* F_ACT  = (float*)(ws + OFF_ACT);
  float* F_VLAD = (float*)(ws + OFF_VLAD);
  float* F_PART = (float*)(ws + OFF_PART);
  float* F_BN1M = (float*)(ws + OFF_BN1M);
  float* F_BN1R = (float*)(ws + OFF_BN1R);
  float* F_ASUM = (float*)(ws + OFF_ASUM);
  float* F_SC1  = (float*)(ws + OFF_SCALE1);
  float* F_SC2  = (float*)(ws + OFF_SCALE2);
  float* F_HID  = (float*)(ws + OFF_HID);
  float* F_VBN  = (float*)(ws + OFF_VLADBN);
  float* F_GAT  = (float*)(ws + OFF_GAT);

  k_gemm<<<(2048 * 64) / 256, 256, 0, stream>>>(F_X4, cw, nullptr, F_ACT0, 2048, 1024, 64);
  k_bnstats<<<64, 256, 0, stream>>>(F_ACT0, 2048, 64, F_BN1M, F_BN1R);
  k_softmax<<<2048, 64, 0, stream>>>(F_ACT0, F_BN1M, F_BN1R, bn1g, bn1b, F_ACT);
  k_colsum<<<8, 64, 0, stream>>>(F_ACT, F_ASUM);
  k_vlad<<<8192, 64, 0, stream>>>(F_ACT, F_X4, F_ASUM, cw2, F_VLAD);
  k_norm1<<<512, 64, 0, stream>>>(F_VLAD, F_SC1);
  k_norm2<<<8, 256, 0, stream>>>(F_VLAD, F_SC1, F_SC2);
  k_vscale<<<(8 * 65536) / 256, 256, 0, stream>>>(F_VLAD, F_SC1, F_SC2);
  k_hidden_partial<<<dim3(4, 128), 256, 0, stream>>>(F_VLAD, hw, F_PART);
  k_hidden_reduce<<<32, 256, 0, stream>>>(F_PART, F_HID);
  k_bn8<<<4, 256, 0, stream>>>(F_HID, bn2g, bn2b, F_VBN);
  k_gemm<<<(8 * 1024) / 256, 256, 0, stream>>>(F_VBN, gw, nullptr, F_GAT, 8, 1024, 1024);
  k_gbn_out<<<4, 256, 0, stream>>>(F_GAT, gbng, gbnb, F_VBN, out + 8192);
}

// Round 2
// 1867.612 us; speedup vs baseline: 1.8745x; 1.8745x over previous
//
#include <hip/hip_runtime.h>
#include <math.h>

// ============================================================================
// SBDD point-cloud network, fp32, bs=8, N_PTS=4096, NB=20, S=1.
// ============================================================================

#define NB_K 20
#define BN_EPS 1e-5f

// ---------------------------------------------------------------------------
// Host-side reproduction of np.random.RandomState(seed).permutation(n)
// ---------------------------------------------------------------------------
namespace {
struct MT19937H {
  unsigned mt[624]; int pos;
  void seed(unsigned s) {
    for (int i = 0; i < 624; i++) { mt[i] = s; s = 1812433253u * (s ^ (s >> 30)) + (unsigned)i + 1u; }
    pos = 624;
  }
  unsigned next() {
    if (pos >= 624) {
      for (int i = 0; i < 624; i++) {
        unsigned y = (mt[i] & 0x80000000u) | (mt[(i + 1) % 624] & 0x7fffffffu);
        unsigned v = mt[(i + 397) % 624] ^ (y >> 1);
        if (y & 1u) v ^= 0x9908b0dfu;
        mt[i] = v;
      }
      pos = 0;
    }
    unsigned y = mt[pos++];
    y ^= y >> 11; y ^= (y << 7) & 0x9d2c5680u; y ^= (y << 15) & 0xefc60000u; y ^= y >> 18;
    return y;
  }
  unsigned interval(unsigned mx) {
    if (mx == 0) return 0;
    unsigned mask = mx;
    mask |= mask >> 1; mask |= mask >> 2; mask |= mask >> 4; mask |= mask >> 8; mask |= mask >> 16;
    unsigned v;
    do { v = next() & mask; } while (v > mx);
    return v;
  }
};
struct Pools {
  int p1[1024];
  int p2[256];
  int arr[4096];
  Pools() {
    MT19937H m;
    m.seed(1);
    for (int i = 0; i < 4096; i++) arr[i] = i;
    for (int i = 4095; i >= 1; i--) {
      int j = (int)m.interval((unsigned)i);
      int t = arr[j]; arr[j] = arr[i]; arr[i] = t;
    }
    for (int i = 0; i < 1024; i++) p1[i] = arr[i];
    m.seed(2);
    for (int i = 0; i < 1024; i++) arr[i] = i;
    for (int i = 1023; i >= 1; i--) {
      int j = (int)m.interval((unsigned)i);
      int t = arr[j]; arr[j] = arr[i]; arr[i] = t;
    }
    for (int i = 0; i < 256; i++) p2[i] = arr[i];
  }
};
Pools g_pools;
}

// ---------------------------------------------------------------------------
// Workspace layout (bytes).
// ---------------------------------------------------------------------------
#define OFF_POOL1   (0u)
#define OFF_POOL2   (16u << 10)
#define OFF_DIRN0   (32u << 10)
#define OFF_DIRN1   (36u << 10)
#define OFF_DIRN2   (40u << 10)
#define OFF_DIRN3   (48u << 10)
#define OFF_DIRN4   (56u << 10)
#define OFF_V2      (128u << 10)
#define OFF_V3      (256u << 10)
#define OFF_BN1M    (288u << 10)
#define OFF_BN1R    (292u << 10)
#define OFF_ASUM    (296u << 10)
#define OFF_SCALE1  (304u << 10)
#define OFF_SCALE2  (312u << 10)
#define OFF_HID     (320u << 10)
#define OFF_VLADBN  (352u << 10)
#define OFF_GAT     (384u << 10)
#define OFF_NB      (1u << 20)          // neighbor idx, reused all stages
#define OFF_X1      (4u << 20)          // 16 MB
#define OFF_X2      (20u << 20)         // 16 MB
#define OFF_X3      (36u << 20)         // 8 MB
#define OFF_X4      (44u << 20)         // 8 MB
#define OFF_KPART   (OFF_X1)            // knn partial top-21 (X1/X2 free during knn)
#define OFF_ACT0    (OFF_X1)
#define OFF_ACT     (OFF_X1 + (1u << 20))
#define OFF_VLAD    (OFF_X1 + (2u << 20))
#define OFF_PART    (OFF_X1 + (8u << 20))

// ---------------------------------------------------------------------------
// dir normalization: l2norm(dirs, axis=0)
// ---------------------------------------------------------------------------
__global__ void k_dirnorm(const float* __restrict__ d0, const float* __restrict__ d1,
                          const float* __restrict__ d2, const float* __restrict__ d3,
                          const float* __restrict__ d4,
                          float* __restrict__ o0, float* __restrict__ o1,
                          float* __restrict__ o2, float* __restrict__ o3,
                          float* __restrict__ o4) {
  int i = blockIdx.x * 256 + threadIdx.x;
  const float* src; float* dst; int F, c;
  if      (i < 32)   { src = d0; dst = o0; F = 32;   c = i; }
  else if (i < 96)   { src = d1; dst = o1; F = 64;   c = i - 32; }
  else if (i < 224)  { src = d2; dst = o2; F = 128;  c = i - 96; }
  else if (i < 480)  { src = d3; dst = o3; F = 256;  c = i - 224; }
  else if (i < 1504) { src = d4; dst = o4; F = 1024; c = i - 480; }
  else return;
  float a = src[c], b = src[F + c], cc = src[2 * F + c];
  float nr = sqrtf((a * a + b * b) + cc * cc);
  float inv = 1.0f / fmaxf(nr, 1e-12f);
  dst[c] = a * inv; dst[F + c] = b * inv; dst[2 * F + c] = cc * inv;
}

// ---------------------------------------------------------------------------
// kNN chunked two-pass.
// Pass kernel: per (query, chunk) compute exact top-21 of the chunk via a
// branchless sorted min/max ladder (dists only), then re-scan the LDS tile
// emitting the 21 accepted indices (visit order = ascending idx).
// Merge kernel: re-rank the NCH*21 survivors exactly; slot 0 = self, dropped.
// Distances use an explicit fma chain so pass1/pass2 are bitwise identical
// and self-dist is exactly 0.
// ---------------------------------------------------------------------------
__device__ __forceinline__ float dist_fma(float xq, float yq, float zq, float sqq,
                                          float cx, float cy, float cz, float cw) {
  float dot = fmaf(xq, cx, fmaf(yq, cy, zq * cz));
  return fmaf(-2.0f, dot, sqq + cw);
}

template <int N, int CHUNK, int NCH>
__global__ void k_knn_part(const float* __restrict__ v, int* __restrict__ part) {
  __shared__ float4 tile[CHUNK];
  int q = blockIdx.x * 64 + threadIdx.x;
  int ch = blockIdx.y;
  int b = blockIdx.z;
  const float* vb = v + (size_t)b * N * 3;
  int cbase = ch * CHUNK;
  for (int j = threadIdx.x; j < CHUNK; j += 64) {
    int g = cbase + j;
    float x = vb[g * 3 + 0], y = vb[g * 3 + 1], z = vb[g * 3 + 2];
    tile[j] = make_float4(x, y, z, fmaf(x, x, fmaf(y, y, z * z)));
  }
  __syncthreads();
  float xq = vb[q * 3 + 0], yq = vb[q * 3 + 1], zq = vb[q * 3 + 2];
  float sqq = fmaf(xq, xq, fmaf(yq, yq, zq * zq));
  float kd[21];
#pragma unroll
  for (int t = 0; t < 21; t++) kd[t] = 3.4e38f;
  // pass 1: branchless pair-insertion ladder
  for (int j = 0; j < CHUNK; j += 2) {
    float4 c0 = tile[j], c1 = tile[j + 1];
    float d0 = dist_fma(xq, yq, zq, sqq, c0.x, c0.y, c0.z, c0.w);
    float d1 = dist_fma(xq, yq, zq, sqq, c1.x, c1.y, c1.z, c1.w);
    float lo = fminf(d0, d1), hi = fmaxf(d0, d1);
#pragma unroll
    for (int t = 20; t >= 2; --t)
      kd[t] = fminf(fminf(kd[t], fmaxf(kd[t - 1], lo)), fmaxf(kd[t - 2], hi));
    kd[1] = fminf(fminf(kd[1], fmaxf(kd[0], lo)), hi);
    kd[0] = fminf(kd[0], lo);
  }
  float T = kd[20];
  // pass 2: emit the 21 accepted indices (ascending idx; >=21 always satisfy <=T)
  int cnt = 0;
  int* pb = part + (((size_t)b * NCH + ch) * 21) * N + q;
  for (int j = 0; j < CHUNK; ++j) {
    float4 c = tile[j];
    float d = dist_fma(xq, yq, zq, sqq, c.x, c.y, c.z, c.w);
    if (d <= T && cnt < 21) { pb[(size_t)cnt * N] = cbase + j; cnt++; }
  }
}

template <int N, int NCH>
__global__ void k_knn_merge(const float* __restrict__ v, const int* __restrict__ part,
                            int* __restrict__ nb) {
  int q = blockIdx.x * 64 + threadIdx.x;
  int b = blockIdx.y;
  const float* vb = v + (size_t)b * N * 3;
  float xq = vb[q * 3 + 0], yq = vb[q * 3 + 1], zq = vb[q * 3 + 2];
  float sqq = fmaf(xq, xq, fmaf(yq, yq, zq * zq));
  float kd[21]; int ki[21];
#pragma unroll
  for (int t = 0; t < 21; t++) { kd[t] = 3.4e38f; ki[t] = 0; }
  for (int ch = 0; ch < NCH; ch++) {
#pragma unroll 3
    for (int s = 0; s < 21; s++) {
      int idx = part[(((size_t)b * NCH + ch) * 21 + s) * N + q];
      float cx = vb[idx * 3 + 0], cy = vb[idx * 3 + 1], cz = vb[idx * 3 + 2];
      float cw = fmaf(cx, cx, fmaf(cy, cy, cz * cz));
      float dist = dist_fma(xq, yq, zq, sqq, cx, cy, cz, cw);
      if (dist < kd[20]) {
#pragma unroll
        for (int t = 20; t >= 1; t--) {
          bool shift = dist < kd[t - 1];
          float nk = shift ? kd[t - 1] : dist;
          int   ni = shift ? ki[t - 1] : idx;
          bool upd = dist < kd[t];
          if (upd) { kd[t] = nk; ki[t] = ni; }
        }
        if (dist < kd[0]) { kd[0] = dist; ki[0] = idx; }
      }
    }
  }
  int* nbq = nb + ((size_t)b * N + q) * NB_K;
#pragma unroll
  for (int t = 0; t < NB_K; t++) nbq[t] = ki[t + 1];  // drop self (rank 0, dist 0)
}

// ---------------------------------------------------------------------------
// conv_surface: fm[b,n,f] = max_k relu(dot(normalize(v_nb - v), dirn0[:,f]))
// ---------------------------------------------------------------------------
__global__ void k_surface(const float* __restrict__ v, const int* __restrict__ nb,
                          const float* __restrict__ dirn, float* __restrict__ out) {
  int idx = blockIdx.x * 64 + threadIdx.x;  // b*4096+n
  int b = idx >> 12, n = idx & 4095;
  const float* vb = v + (size_t)b * 4096 * 3;
  float xq = vb[n * 3 + 0], yq = vb[n * 3 + 1], zq = vb[n * 3 + 2];
  float mx[32];
#pragma unroll
  for (int f = 0; f < 32; f++) mx[f] = 0.0f;
  for (int k = 0; k < NB_K; k++) {
    int j = nb[(size_t)idx * NB_K + k];
    float dx = vb[j * 3 + 0] - xq, dy = vb[j * 3 + 1] - yq, dz = vb[j * 3 + 2] - zq;
    float nr = sqrtf((dx * dx + dy * dy) + dz * dz);
    float inv = 1.0f / fmaxf(nr, 1e-12f);
    dx *= inv; dy *= inv; dz *= inv;
#pragma unroll
    for (int f = 0; f < 32; f++) {
      float th = dx * dirn[f] + dy * dirn[32 + f] + dz * dirn[64 + f];
      th = fmaxf(th, 0.0f);
      mx[f] = fmaxf(mx[f], th);
    }
  }
#pragma unroll
  for (int f = 0; f < 32; f++) out[(size_t)idx * 32 + f] = mx[f];
}

// ---------------------------------------------------------------------------
// GEMM, 4 outputs/thread along C, compile-time K: out[r,c] = A[r,:]·W[:,c]+bias
// ---------------------------------------------------------------------------
template <int K>
__global__ void k_gemm4(const float* __restrict__ A, const float* __restrict__ W,
                        const float* __restrict__ bias, float* __restrict__ out,
                        int R, int C) {
  int idx = blockIdx.x * 256 + threadIdx.x;
  int c4 = C >> 2;
  if (idx >= R * c4) return;
  int r = idx / c4, c = (idx - r * c4) << 2;
  const float* a = A + (size_t)r * K;
  float4 acc;
  if (bias) acc = *(const float4*)(bias + c);
  else acc = make_float4(0.f, 0.f, 0.f, 0.f);
#pragma unroll 8
  for (int k = 0; k < K; k++) {
    float av = a[k];
    float4 wv = *(const float4*)(W + (size_t)k * C + c);
    acc.x = fmaf(av, wv.x, acc.x);
    acc.y = fmaf(av, wv.y, acc.y);
    acc.z = fmaf(av, wv.z, acc.z);
    acc.w = fmaf(av, wv.w, acc.w);
  }
  *(float4*)(out + (size_t)r * C + c) = acc;
}

// ---------------------------------------------------------------------------
// conv_layer combine: out = fc + max_k(relu(d_k . dir_c) * fs_k)  [optional relu]
// ---------------------------------------------------------------------------
template <int COUT, int CPT, bool RELU>
__global__ void k_combine(const float* __restrict__ v, const int* __restrict__ nb,
                          const float* __restrict__ fo, const float* __restrict__ dirn,
                          float* __restrict__ out, int N) {
  constexpr int THREADS = COUT / CPT;
  int bn = blockIdx.x;
  int b = bn / N, n = bn - b * N;
  __shared__ float ds[NB_K][3];
  __shared__ int nbs[NB_K];
  const float* vb = v + (size_t)b * N * 3;
  if (threadIdx.x < NB_K) {
    int j = nb[(size_t)bn * NB_K + threadIdx.x];
    nbs[threadIdx.x] = j;
    float xq = vb[n * 3 + 0], yq = vb[n * 3 + 1], zq = vb[n * 3 + 2];
    float dx = vb[j * 3 + 0] - xq, dy = vb[j * 3 + 1] - yq, dz = vb[j * 3 + 2] - zq;
    float nr = sqrtf((dx * dx + dy * dy) + dz * dz);
    float inv = 1.0f / fmaxf(nr, 1e-12f);
    ds[threadIdx.x][0] = dx * inv;
    ds[threadIdx.x][1] = dy * inv;
    ds[threadIdx.x][2] = dz * inv;
  }
  __syncthreads();
#pragma unroll
  for (int cc = 0; cc < CPT; cc++) {
    int c = threadIdx.x + cc * THREADS;
    float w0 = dirn[c], w1 = dirn[COUT + c], w2 = dirn[2 * COUT + c];
    float acc = -3.4e38f;
    for (int k = 0; k < NB_K; k++) {
      float th = ds[k][0] * w0 + ds[k][1] * w1 + ds[k][2] * w2;
      th = fmaxf(th, 0.0f);
      float fs = fo[((size_t)b * N + nbs[k]) * (2 * COUT) + COUT + c];
      acc = fmaxf(acc, th * fs);
    }
    float res = fo[(size_t)bn * (2 * COUT) + c] + acc;
    if (RELU) res = fmaxf(res, 0.0f);
    out[(size_t)bn * COUT + c] = res;
  }
}

// ---------------------------------------------------------------------------
// gather-max pooling over neighbors
// ---------------------------------------------------------------------------
template <int C>
__global__ void k_gathermax(const float* __restrict__ fm, const int* __restrict__ nb,
                            float* __restrict__ out, int N) {
  int bn = blockIdx.x;
  int b = bn / N;
  __shared__ int nbs[NB_K];
  if (threadIdx.x < NB_K) nbs[threadIdx.x] = nb[(size_t)bn * NB_K + threadIdx.x];
  __syncthreads();
  int c = threadIdx.x;
  float acc = -3.4e38f;
  for (int k = 0; k < NB_K; k++)
    acc = fmaxf(acc, fm[((size_t)b * N + nbs[k]) * C + c]);
  out[(size_t)bn * C + c] = acc;
}

// ---------------------------------------------------------------------------
// pool-index gather
// ---------------------------------------------------------------------------
__global__ void k_poolgather(const float* __restrict__ in, const int* __restrict__ pool,
                             float* __restrict__ out, int n_in, int n_out, int C) {
  int idx = blockIdx.x * 256 + threadIdx.x;
  if (idx >= 8 * n_out * C) return;
  int c = idx % C; int t = idx / C; int i = t % n_out; int b = t / n_out;
  out[idx] = in[((size_t)b * n_in + pool[i]) * C + c];
}

// ---------------------------------------------------------------------------
// GeM pooling
// ---------------------------------------------------------------------------
__global__ void k_gem(const float* __restrict__ fm4, const float* __restrict__ gp,
                      float* __restrict__ y) {
  int idx = blockIdx.x * 256 + threadIdx.x;  // b*1024+f
  int b = idx >> 10, f = idx & 1023;
  float p = gp[0];
  float s = 0.0f;
  for (int n = 0; n < 256; n++) {
    float val = fmaxf(fm4[((size_t)b * 256 + n) * 1024 + f], 1e-6f);
    s += powf(val, p);
  }
  y[idx] = powf(s * (1.0f / 256.0f), 1.0f / p);
}

// ---------------------------------------------------------------------------
// NetVLAD pieces
// ---------------------------------------------------------------------------
__global__ void k_bnstats(const float* __restrict__ x, int R, int C,
                          float* __restrict__ mean, float* __restrict__ rstd) {
  int c = blockIdx.x;
  __shared__ float red[256];
  float s = 0.0f;
  for (int r = threadIdx.x; r < R; r += 256) s += x[(size_t)r * C + c];
  red[threadIdx.x] = s; __syncthreads();
  for (int st = 128; st > 0; st >>= 1) {
    if (threadIdx.x < st) red[threadIdx.x] += red[threadIdx.x + st];
    __syncthreads();
  }
  float m = red[0] / (float)R;
  __syncthreads();
  float s2 = 0.0f;
  for (int r = threadIdx.x; r < R; r += 256) {
    float d = x[(size_t)r * C + c] - m; s2 += d * d;
  }
  red[threadIdx.x] = s2; __syncthreads();
  for (int st = 128; st > 0; st >>= 1) {
    if (threadIdx.x < st) red[threadIdx.x] += red[threadIdx.x + st];
    __syncthreads();
  }
  if (threadIdx.x == 0) {
    mean[c] = m;
    rstd[c] = 1.0f / sqrtf(red[0] / (float)R + BN_EPS);
  }
}

__global__ void k_softmax(const float* __restrict__ a0, const float* __restrict__ mean,
                          const float* __restrict__ rstd, const float* __restrict__ g,
                          const float* __restrict__ bb, float* __restrict__ act) {
  int r = blockIdx.x, c = threadIdx.x;
  float x = (a0[(size_t)r * 64 + c] - mean[c]) * rstd[c] * g[c] + bb[c];
  float mx = x;
  for (int off = 32; off > 0; off >>= 1) mx = fmaxf(mx, __shfl_xor(mx, off));
  float e = expf(x - mx);
  float sm = e;
  for (int off = 32; off > 0; off >>= 1) sm += __shfl_xor(sm, off);
  act[(size_t)r * 64 + c] = e / sm;
}

__global__ void k_colsum(const float* __restrict__ act, float* __restrict__ asum) {
  int b = blockIdx.x, k = threadIdx.x;
  float s = 0.0f;
  for (int m = 0; m < 256; m++) s += act[((size_t)b * 256 + m) * 64 + k];
  asum[b * 64 + k] = s;
}

__global__ void k_vlad(const float* __restrict__ act, const float* __restrict__ xv,
                       const float* __restrict__ asum, const float* __restrict__ cw2,
                       float* __restrict__ vlad) {
  int bf = blockIdx.x;              // b*1024+f
  int b = bf >> 10, f = bf & 1023;
  __shared__ float xs[256];
  for (int m = threadIdx.x; m < 256; m += 64)
    xs[m] = xv[((size_t)b * 256 + m) * 1024 + f];
  __syncthreads();
  int k = threadIdx.x;
  float acc = 0.0f;
  for (int m = 0; m < 256; m++) acc += act[((size_t)b * 256 + m) * 64 + k] * xs[m];
  vlad[(size_t)bf * 64 + k] = acc - asum[b * 64 + k] * cw2[f * 64 + k];
}

__global__ void k_norm1(const float* __restrict__ vlad, float* __restrict__ scale1) {
  int bk = blockIdx.x;  // b*64+k
  int b = bk >> 6, k = bk & 63;
  float s = 0.0f;
  for (int f = threadIdx.x; f < 1024; f += 64) {
    float val = vlad[((size_t)b * 1024 + f) * 64 + k];
    s += val * val;
  }
  for (int off = 32; off > 0; off >>= 1) s += __shfl_xor(s, off);
  if (threadIdx.x == 0) scale1[bk] = 1.0f / fmaxf(sqrtf(s), 1e-12f);
}

__global__ void k_norm2(const float* __restrict__ vlad, const float* __restrict__ scale1,
                        float* __restrict__ scale2) {
  int b = blockIdx.x;
  __shared__ float red[256];
  float s = 0.0f;
  for (int i = threadIdx.x; i < 65536; i += 256) {
    float val = vlad[(size_t)b * 65536 + i] * scale1[b * 64 + (i & 63)];
    s += val * val;
  }
  red[threadIdx.x] = s; __syncthreads();
  for (int st = 128; st > 0; st >>= 1) {
    if (threadIdx.x < st) red[threadIdx.x] += red[threadIdx.x + st];
    __syncthreads();
  }
  if (threadIdx.x == 0) scale2[b] = 1.0f / fmaxf(sqrtf(red[0]), 1e-12f);
}

__global__ void k_vscale(float* __restrict__ vlad, const float* __restrict__ scale1,
                         const float* __restrict__ scale2) {
  int idx = blockIdx.x * 256 + threadIdx.x;
  int b = idx >> 16; int r = idx & 65535;
  vlad[idx] = vlad[idx] * scale1[b * 64 + (r & 63)] * scale2[b];
}

__global__ void k_hidden_partial(const float* __restrict__ vlad, const float* __restrict__ hw,
                                 float* __restrict__ partial) {
  __shared__ float vs[8][512];
  int cg = blockIdx.x;   // 0..3
  int kb = blockIdx.y;   // 0..127
  int col = cg * 256 + threadIdx.x;
  int k0 = kb * 512;
  for (int i = threadIdx.x; i < 8 * 512; i += 256) {
    int b = i >> 9, k = i & 511;
    vs[b][k] = vlad[(size_t)b * 65536 + k0 + k];
  }
  __syncthreads();
  float acc[8] = {0, 0, 0, 0, 0, 0, 0, 0};
  for (int k = 0; k < 512; k++) {
    float w = hw[(size_t)(k0 + k) * 1024 + col];
#pragma unroll
    for (int b = 0; b < 8; b++) acc[b] += vs[b][k] * w;
  }
#pragma unroll
  for (int b = 0; b < 8; b++)
    partial[((size_t)kb * 8 + b) * 1024 + col] = acc[b];
}

__global__ void k_hidden_reduce(const float* __restrict__ partial, float* __restrict__ hid) {
  int idx = blockIdx.x * 256 + threadIdx.x;  // b*1024+c
  int b = idx >> 10, c = idx & 1023;
  float s = 0.0f;
  for (int kb = 0; kb < 128; kb++) s += partial[((size_t)kb * 8 + b) * 1024 + c];
  hid[idx] = s;
}

__global__ void k_bn8(const float* __restrict__ x, const float* __restrict__ g,
                      const float* __restrict__ bb, float* __restrict__ out) {
  int c = blockIdx.x * 256 + threadIdx.x;
  if (c >= 1024) return;
  float v[8]; float s = 0.0f;
#pragma unroll
  for (int b = 0; b < 8; b++) { v[b] = x[b * 1024 + c]; s += v[b]; }
  float m = s * 0.125f; float s2 = 0.0f;
#pragma unroll
  for (int b = 0; b < 8; b++) { float d = v[b] - m; s2 += d * d; }
  float rstd = 1.0f / sqrtf(s2 * 0.125f + BN_EPS);
#pragma unroll
  for (int b = 0; b < 8; b++) out[b * 1024 + c] = (v[b] - m) * rstd * g[c] + bb[c];
}

__global__ void k_gbn_out(const float* __restrict__ gat, const float* __restrict__ g,
                          const float* __restrict__ bb, const float* __restrict__ vladbn,
                          float* __restrict__ desc) {
  int c = blockIdx.x * 256 + threadIdx.x;
  if (c >= 1024) return;
  float v[8]; float s = 0.0f;
#pragma unroll
  for (int b = 0; b < 8; b++) { v[b] = gat[b * 1024 + c]; s += v[b]; }
  float m = s * 0.125f; float s2 = 0.0f;
#pragma unroll
  for (int b = 0; b < 8; b++) { float d = v[b] - m; s2 += d * d; }
  float rstd = 1.0f / sqrtf(s2 * 0.125f + BN_EPS);
#pragma unroll
  for (int b = 0; b < 8; b++) {
    float x = (v[b] - m) * rstd * g[c] + bb[c];
    float gate = 1.0f / (1.0f + expf(-x));
    desc[b * 1024 + c] = vladbn[b * 1024 + c] * gate;
  }
}

// ---------------------------------------------------------------------------
// launch
// ---------------------------------------------------------------------------
extern "C" void kernel_launch(void* const* d_in, const int* in_sizes, int n_in,
                              void* d_out, int out_size, void* d_ws, size_t ws_size,
                              hipStream_t stream) {
  (void)in_sizes; (void)n_in; (void)out_size; (void)ws_size;
  const float* x    = (const float*)d_in[0];
  const float* dir0 = (const float*)d_in[1];
  const float* W1   = (const float*)d_in[2];
  const float* b1   = (const float*)d_in[3];
  const float* dir1 = (const float*)d_in[4];
  const float* W2   = (const float*)d_in[5];
  const float* b2   = (const float*)d_in[6];
  const float* dir2 = (const float*)d_in[7];
  const float* W3   = (const float*)d_in[8];
  const float* b3   = (const float*)d_in[9];
  const float* dir3 = (const float*)d_in[10];
  const float* W4   = (const float*)d_in[11];
  const float* b4   = (const float*)d_in[12];
  const float* dir4 = (const float*)d_in[13];
  const float* gemp = (const float*)d_in[14];
  const float* cw   = (const float*)d_in[15];
  const float* cw2  = (const float*)d_in[16];
  const float* hw   = (const float*)d_in[17];
  const float* bn1g = (const float*)d_in[18];
  const float* bn1b = (const float*)d_in[19];
  const float* bn2g = (const float*)d_in[20];
  const float* bn2b = (const float*)d_in[21];
  const float* gw   = (const float*)d_in[22];
  const float* gbng = (const float*)d_in[23];
  const float* gbnb = (const float*)d_in[24];
  float* out = (float*)d_out;
  char* ws = (char*)d_ws;

  float* F_DIRN0 = (float*)(ws + OFF_DIRN0);
  float* F_DIRN1 = (float*)(ws + OFF_DIRN1);
  float* F_DIRN2 = (float*)(ws + OFF_DIRN2);
  float* F_DIRN3 = (float*)(ws + OFF_DIRN3);
  float* F_DIRN4 = (float*)(ws + OFF_DIRN4);
  int*   I_POOL1 = (int*)(ws + OFF_POOL1);
  int*   I_POOL2 = (int*)(ws + OFF_POOL2);
  int*   I_NB    = (int*)(ws + OFF_NB);
  int*   I_KPART = (int*)(ws + OFF_KPART);
  float* F_V2    = (float*)(ws + OFF_V2);
  float* F_V3    = (float*)(ws + OFF_V3);
  float* F_X1    = (float*)(ws + OFF_X1);
  float* F_X2    = (float*)(ws + OFF_X2);
  float* F_X3    = (float*)(ws + OFF_X3);
  float* F_X4    = (float*)(ws + OFF_X4);

  hipMemcpyAsync(I_POOL1, g_pools.p1, sizeof(g_pools.p1), hipMemcpyHostToDevice, stream);
  hipMemcpyAsync(I_POOL2, g_pools.p2, sizeof(g_pools.p2), hipMemcpyHostToDevice, stream);

  k_dirnorm<<<6, 256, 0, stream>>>(dir0, dir1, dir2, dir3, dir4,
                                   F_DIRN0, F_DIRN1, F_DIRN2, F_DIRN3, F_DIRN4);

  // ---- level 0: 4096 pts ----
  k_knn_part<4096, 512, 8><<<dim3(64, 8, 8), 64, 0, stream>>>(x, I_KPART);
  k_knn_merge<4096, 8><<<dim3(64, 8), 64, 0, stream>>>(x, I_KPART, I_NB);
  k_surface<<<512, 64, 0, stream>>>(x, I_NB, F_DIRN0, F_X3);
  k_gemm4<32><<<(32768 * 32 + 255) / 256, 256, 0, stream>>>(F_X3, W1, b1, F_X1, 32768, 128);
  k_combine<64, 1, true><<<32768, 64, 0, stream>>>(x, I_NB, F_X1, F_DIRN1, F_X4, 4096);
  k_gathermax<64><<<32768, 64, 0, stream>>>(F_X4, I_NB, F_X2, 4096);
  k_poolgather<<<(8 * 1024 * 3 + 255) / 256, 256, 0, stream>>>(x, I_POOL1, F_V2, 4096, 1024, 3);
  k_poolgather<<<(8 * 1024 * 64 + 255) / 256, 256, 0, stream>>>(F_X2, I_POOL1, F_X3, 4096, 1024, 64);

  // ---- level 1: 1024 pts ----
  k_knn_part<1024, 128, 8><<<dim3(16, 8, 8), 64, 0, stream>>>(F_V2, I_KPART);
  k_knn_merge<1024, 8><<<dim3(16, 8), 64, 0, stream>>>(F_V2, I_KPART, I_NB);
  k_gemm4<64><<<(8192 * 64 + 255) / 256, 256, 0, stream>>>(F_X3, W2, b2, F_X4, 8192, 256);
  k_combine<128, 1, true><<<8192, 128, 0, stream>>>(F_V2, I_NB, F_X4, F_DIRN2, F_X1, 1024);
  k_gemm4<128><<<(8192 * 128 + 255) / 256, 256, 0, stream>>>(F_X1, W3, b3, F_X2, 8192, 512);
  k_combine<256, 1, true><<<8192, 256, 0, stream>>>(F_V2, I_NB, F_X2, F_DIRN3, F_X4, 1024);
  k_gathermax<256><<<8192, 256, 0, stream>>>(F_X4, I_NB, F_X1, 1024);
  k_poolgather<<<(8 * 256 * 3 + 255) / 256, 256, 0, stream>>>(F_V2, I_POOL2, F_V3, 1024, 256, 3);
  k_poolgather<<<(8 * 256 * 256 + 255) / 256, 256, 0, stream>>>(F_X1, I_POOL2, F_X3, 1024, 256, 256);

  // ---- level 2: 256 pts ----
  k_knn_part<256, 64, 4><<<dim3(4, 4, 8), 64, 0, stream>>>(F_V3, I_KPART);
  k_knn_merge<256, 4><<<dim3(4, 8), 64, 0, stream>>>(F_V3, I_KPART, I_NB);
  k_gemm4<256><<<(2048 * 512 + 255) / 256, 256, 0, stream>>>(F_X3, W4, b4, F_X2, 2048, 2048);
  k_combine<1024, 4, false><<<2048, 256, 0, stream>>>(F_V3, I_NB, F_X2, F_DIRN4, F_X4, 256);

  // ---- GeM head -> out[0:8192] ----
  k_gem<<<32, 256, 0, stream>>>(F_X4, gemp, out);

  // ---- NetVLAD head -> out[8192:16384] ----
  float* F_ACT0 = (float*)(ws + OFF_ACT0);
  float* F_ACT  = (float*)(ws + OFF_ACT);
  float* F_VLAD = (float*)(ws + OFF_VLAD);
  float* F_PART = (float*)(ws + OFF_PART);
  float* F_BN1M = (float*)(ws + OFF_BN1M);
  float* F_BN1R = (float*)(ws + OFF_BN1R);
  float* F_ASUM = (float*)(ws + OFF_ASUM);
  float* F_SC1  = (float*)(ws + OFF_SCALE1);
  float* F_SC2  = (float*)(ws + OFF_SCALE2);
  float* F_HID  = (float*)(ws + OFF_HID);
  float* F_VBN  = (float*)(ws + OFF_VLADBN);
  float* F_GAT  = (float*)(ws + OFF_GAT);

  k_gemm4<1024><<<(2048 * 16 + 255) / 256, 256, 0, stream>>>(F_X4, cw, nullptr, F_ACT0, 2048, 64);
  k_bnstats<<<64, 256, 0, stream>>>(F_ACT0, 2048, 64, F_BN1M, F_BN1R);
  k_softmax<<<2048, 64, 0, stream>>>(F_ACT0, F_BN1M, F_BN1R, bn1g, bn1b, F_ACT);
  k_colsum<<<8, 64, 0, stream>>>(F_ACT, F_ASUM);
  k_vlad<<<8192, 64, 0, stream>>>(F_ACT, F_X4, F_ASUM, cw2, F_VLAD);
  k_norm1<<<512, 64, 0, stream>>>(F_VLAD, F_SC1);
  k_norm2<<<8, 256, 0, stream>>>(F_VLAD, F_SC1, F_SC2);
  k_vscale<<<(8 * 65536) / 256, 256, 0, stream>>>(F_VLAD, F_SC1, F_SC2);
  k_hidden_partial<<<dim3(4, 128), 256, 0, stream>>>(F_VLAD, hw, F_PART);
  k_hidden_reduce<<<32, 256, 0, stream>>>(F_PART, F_HID);
  k_bn8<<<4, 256, 0, stream>>>(F_HID, bn2g, bn2b, F_VBN);
  k_gemm4<1024><<<(8 * 256 + 255) / 256, 256, 0, stream>>>(F_VBN, gw, nullptr, F_GAT, 8, 1024);
  k_gbn_out<<<4, 256, 0, stream>>>(F_GAT, gbng, gbnb, F_VBN, out + 8192);
}

// Round 3
// 1434.264 us; speedup vs baseline: 2.4409x; 1.3021x over previous
//
#include <hip/hip_runtime.h>
#include <math.h>

// ============================================================================
// SBDD point-cloud network, fp32, bs=8, N_PTS=4096, NB=20, S=1.
// ============================================================================

#define NB_K 20
#define BN_EPS 1e-5f

// ---------------------------------------------------------------------------
// Host-side reproduction of np.random.RandomState(seed).permutation(n)
// ---------------------------------------------------------------------------
namespace {
struct MT19937H {
  unsigned mt[624]; int pos;
  void seed(unsigned s) {
    for (int i = 0; i < 624; i++) { mt[i] = s; s = 1812433253u * (s ^ (s >> 30)) + (unsigned)i + 1u; }
    pos = 624;
  }
  unsigned next() {
    if (pos >= 624) {
      for (int i = 0; i < 624; i++) {
        unsigned y = (mt[i] & 0x80000000u) | (mt[(i + 1) % 624] & 0x7fffffffu);
        unsigned v = mt[(i + 397) % 624] ^ (y >> 1);
        if (y & 1u) v ^= 0x9908b0dfu;
        mt[i] = v;
      }
      pos = 0;
    }
    unsigned y = mt[pos++];
    y ^= y >> 11; y ^= (y << 7) & 0x9d2c5680u; y ^= (y << 15) & 0xefc60000u; y ^= y >> 18;
    return y;
  }
  unsigned interval(unsigned mx) {
    if (mx == 0) return 0;
    unsigned mask = mx;
    mask |= mask >> 1; mask |= mask >> 2; mask |= mask >> 4; mask |= mask >> 8; mask |= mask >> 16;
    unsigned v;
    do { v = next() & mask; } while (v > mx);
    return v;
  }
};
struct Pools {
  int p1[1024];
  int p2[256];
  int arr[4096];
  Pools() {
    MT19937H m;
    m.seed(1);
    for (int i = 0; i < 4096; i++) arr[i] = i;
    for (int i = 4095; i >= 1; i--) {
      int j = (int)m.interval((unsigned)i);
      int t = arr[j]; arr[j] = arr[i]; arr[i] = t;
    }
    for (int i = 0; i < 1024; i++) p1[i] = arr[i];
    m.seed(2);
    for (int i = 0; i < 1024; i++) arr[i] = i;
    for (int i = 1023; i >= 1; i--) {
      int j = (int)m.interval((unsigned)i);
      int t = arr[j]; arr[j] = arr[i]; arr[i] = t;
    }
    for (int i = 0; i < 256; i++) p2[i] = arr[i];
  }
};
Pools g_pools;
}

// ---------------------------------------------------------------------------
// Workspace layout (bytes).
// ---------------------------------------------------------------------------
#define OFF_POOL1   (0u)
#define OFF_POOL2   (16u << 10)
#define OFF_DIRN0   (32u << 10)
#define OFF_DIRN1   (36u << 10)
#define OFF_DIRN2   (40u << 10)
#define OFF_DIRN3   (48u << 10)
#define OFF_DIRN4   (56u << 10)
#define OFF_V2      (128u << 10)
#define OFF_V3      (256u << 10)
#define OFF_BN1M    (288u << 10)
#define OFF_BN1R    (292u << 10)
#define OFF_ASUM    (296u << 10)
#define OFF_SCALE1  (304u << 10)
#define OFF_SCALE2  (312u << 10)
#define OFF_HID     (320u << 10)
#define OFF_VLADBN  (352u << 10)
#define OFF_GAT     (384u << 10)
#define OFF_NB      (1u << 20)          // neighbor idx, reused all stages
#define OFF_X1      (4u << 20)          // 16 MB
#define OFF_X2      (20u << 20)         // 16 MB
#define OFF_X3      (36u << 20)         // 8 MB
#define OFF_X4      (44u << 20)         // 8 MB
// knn4096 scratch (X regions free during knn): surv 32MB @X1, cnt 1MB @X3, T0 @X4
#define OFF_KSURV   (OFF_X1)
#define OFF_KCNT    (OFF_X3)
#define OFF_KT0     (OFF_X4)
#define OFF_KPART   (OFF_X1)            // small-level knn partials
#define OFF_ACT0    (OFF_X1)
#define OFF_ACT     (OFF_X1 + (1u << 20))
#define OFF_VLAD    (OFF_X1 + (2u << 20))
#define OFF_PART    (OFF_X1 + (8u << 20))

// ---------------------------------------------------------------------------
// dir normalization: l2norm(dirs, axis=0)
// ---------------------------------------------------------------------------
__global__ void k_dirnorm(const float* __restrict__ d0, const float* __restrict__ d1,
                          const float* __restrict__ d2, const float* __restrict__ d3,
                          const float* __restrict__ d4,
                          float* __restrict__ o0, float* __restrict__ o1,
                          float* __restrict__ o2, float* __restrict__ o3,
                          float* __restrict__ o4) {
  int i = blockIdx.x * 256 + threadIdx.x;
  const float* src; float* dst; int F, c;
  if      (i < 32)   { src = d0; dst = o0; F = 32;   c = i; }
  else if (i < 96)   { src = d1; dst = o1; F = 64;   c = i - 32; }
  else if (i < 224)  { src = d2; dst = o2; F = 128;  c = i - 96; }
  else if (i < 480)  { src = d3; dst = o3; F = 256;  c = i - 224; }
  else if (i < 1504) { src = d4; dst = o4; F = 1024; c = i - 480; }
  else return;
  float a = src[c], b = src[F + c], cc = src[2 * F + c];
  float nr = sqrtf((a * a + b * b) + cc * cc);
  float inv = 1.0f / fmaxf(nr, 1e-12f);
  dst[c] = a * inv; dst[F + c] = b * inv; dst[2 * F + c] = cc * inv;
}

// ---------------------------------------------------------------------------
// kNN. dist via fixed fma chain so all kernels agree bitwise; self-dist == 0.
// ---------------------------------------------------------------------------
__device__ __forceinline__ float dist_fma(float xq, float yq, float zq, float sqq,
                                          float cx, float cy, float cz, float cw) {
  float dot = fmaf(xq, cx, fmaf(yq, cy, zq * cz));
  return fmaf(-2.0f, dot, sqq + cw);
}

// --- knn4096 scheme: sample (exact 21st of first 512) -> filter -> merge ---
template <int N, int SAMPLE>
__global__ void k_knn_sample(const float* __restrict__ v, float* __restrict__ T0) {
  __shared__ float4 tile[SAMPLE];
  int q = blockIdx.x * 64 + threadIdx.x;
  int b = blockIdx.y;
  const float* vb = v + (size_t)b * N * 3;
  for (int j = threadIdx.x; j < SAMPLE; j += 64) {
    float x = vb[j * 3 + 0], y = vb[j * 3 + 1], z = vb[j * 3 + 2];
    tile[j] = make_float4(x, y, z, fmaf(x, x, fmaf(y, y, z * z)));
  }
  __syncthreads();
  float xq = vb[q * 3 + 0], yq = vb[q * 3 + 1], zq = vb[q * 3 + 2];
  float sqq = fmaf(xq, xq, fmaf(yq, yq, zq * zq));
  float kd[21];
#pragma unroll
  for (int t = 0; t < 21; t++) kd[t] = 3.4e38f;
  for (int j = 0; j < SAMPLE; j += 2) {
    float4 c0 = tile[j], c1 = tile[j + 1];
    float d0 = dist_fma(xq, yq, zq, sqq, c0.x, c0.y, c0.z, c0.w);
    float d1 = dist_fma(xq, yq, zq, sqq, c1.x, c1.y, c1.z, c1.w);
    float lo = fminf(d0, d1), hi = fmaxf(d0, d1);
#pragma unroll
    for (int t = 20; t >= 2; --t)
      kd[t] = fminf(fminf(kd[t], fmaxf(kd[t - 1], lo)), fmaxf(kd[t - 2], hi));
    kd[1] = fminf(fminf(kd[1], fmaxf(kd[0], lo)), hi);
    kd[0] = fminf(kd[0], lo);
  }
  T0[(size_t)b * N + q] = kd[20];  // >= global 21st-smallest (sample superset bound)
}

template <int N, int CHUNK, int NCH, int SLOTS>
__global__ void k_knn_filter(const float* __restrict__ v, const float* __restrict__ T0,
                             unsigned short* __restrict__ surv, int* __restrict__ cnt) {
  __shared__ float4 tile[CHUNK];
  int q = blockIdx.x * 64 + threadIdx.x;
  int ch = blockIdx.y;
  int b = blockIdx.z;
  const float* vb = v + (size_t)b * N * 3;
  int cbase = ch * CHUNK;
  for (int j = threadIdx.x; j < CHUNK; j += 64) {
    int g = cbase + j;
    float x = vb[g * 3 + 0], y = vb[g * 3 + 1], z = vb[g * 3 + 2];
    tile[j] = make_float4(x, y, z, fmaf(x, x, fmaf(y, y, z * z)));
  }
  __syncthreads();
  float xq = vb[q * 3 + 0], yq = vb[q * 3 + 1], zq = vb[q * 3 + 2];
  float sqq = fmaf(xq, xq, fmaf(yq, yq, zq * zq));
  float T = T0[(size_t)b * N + q];
  int c = 0;
  unsigned short* sb = surv + ((size_t)b * NCH + ch) * SLOTS * N + q;
  for (int j = 0; j < CHUNK; ++j) {
    float4 cd = tile[j];
    float d = dist_fma(xq, yq, zq, sqq, cd.x, cd.y, cd.z, cd.w);
    if (d <= T && c < SLOTS) {
      sb[(size_t)c * N] = (unsigned short)(cbase + j);
      c++;
    }
  }
  cnt[((size_t)b * NCH + ch) * N + q] = c;
}

template <int N, int NCH, int SLOTS>
__global__ void k_knn_merge2(const float* __restrict__ v, const unsigned short* __restrict__ surv,
                             const int* __restrict__ cnt, int* __restrict__ nb) {
  int q = blockIdx.x * 64 + threadIdx.x;
  int b = blockIdx.y;
  const float* vb = v + (size_t)b * N * 3;
  float xq = vb[q * 3 + 0], yq = vb[q * 3 + 1], zq = vb[q * 3 + 2];
  float sqq = fmaf(xq, xq, fmaf(yq, yq, zq * zq));
  float kd[21]; int ki[21];
#pragma unroll
  for (int t = 0; t < 21; t++) { kd[t] = 3.4e38f; ki[t] = 0; }
  for (int ch = 0; ch < NCH; ch++) {
    int cn = cnt[((size_t)b * NCH + ch) * N + q];
    const unsigned short* sb = surv + ((size_t)b * NCH + ch) * SLOTS * N + q;
    for (int s = 0; s < cn; s++) {
      int idx = sb[(size_t)s * N];
      float cx = vb[idx * 3 + 0], cy = vb[idx * 3 + 1], cz = vb[idx * 3 + 2];
      float cw = fmaf(cx, cx, fmaf(cy, cy, cz * cz));
      float dist = dist_fma(xq, yq, zq, sqq, cx, cy, cz, cw);
      if (dist < kd[20]) {
#pragma unroll
        for (int t = 20; t >= 1; t--) {
          bool shift = dist < kd[t - 1];
          float nk = shift ? kd[t - 1] : dist;
          int   ni = shift ? ki[t - 1] : idx;
          bool upd = dist < kd[t];
          if (upd) { kd[t] = nk; ki[t] = ni; }
        }
        if (dist < kd[0]) { kd[0] = dist; ki[0] = idx; }
      }
    }
  }
  int* nbq = nb + ((size_t)b * N + q) * NB_K;
#pragma unroll
  for (int t = 0; t < NB_K; t++) nbq[t] = ki[t + 1];  // drop self (rank 0, dist 0)
}

// --- small-level knn (1024/256): proven two-pass chunked ladder ---
template <int N, int CHUNK, int NCH>
__global__ void k_knn_part(const float* __restrict__ v, int* __restrict__ part) {
  __shared__ float4 tile[CHUNK];
  int q = blockIdx.x * 64 + threadIdx.x;
  int ch = blockIdx.y;
  int b = blockIdx.z;
  const float* vb = v + (size_t)b * N * 3;
  int cbase = ch * CHUNK;
  for (int j = threadIdx.x; j < CHUNK; j += 64) {
    int g = cbase + j;
    float x = vb[g * 3 + 0], y = vb[g * 3 + 1], z = vb[g * 3 + 2];
    tile[j] = make_float4(x, y, z, fmaf(x, x, fmaf(y, y, z * z)));
  }
  __syncthreads();
  float xq = vb[q * 3 + 0], yq = vb[q * 3 + 1], zq = vb[q * 3 + 2];
  float sqq = fmaf(xq, xq, fmaf(yq, yq, zq * zq));
  float kd[21];
#pragma unroll
  for (int t = 0; t < 21; t++) kd[t] = 3.4e38f;
  for (int j = 0; j < CHUNK; j += 2) {
    float4 c0 = tile[j], c1 = tile[j + 1];
    float d0 = dist_fma(xq, yq, zq, sqq, c0.x, c0.y, c0.z, c0.w);
    float d1 = dist_fma(xq, yq, zq, sqq, c1.x, c1.y, c1.z, c1.w);
    float lo = fminf(d0, d1), hi = fmaxf(d0, d1);
#pragma unroll
    for (int t = 20; t >= 2; --t)
      kd[t] = fminf(fminf(kd[t], fmaxf(kd[t - 1], lo)), fmaxf(kd[t - 2], hi));
    kd[1] = fminf(fminf(kd[1], fmaxf(kd[0], lo)), hi);
    kd[0] = fminf(kd[0], lo);
  }
  float T = kd[20];
  int cnt = 0;
  int* pb = part + (((size_t)b * NCH + ch) * 21) * N + q;
  for (int j = 0; j < CHUNK; ++j) {
    float4 c = tile[j];
    float d = dist_fma(xq, yq, zq, sqq, c.x, c.y, c.z, c.w);
    if (d <= T && cnt < 21) { pb[(size_t)cnt * N] = cbase + j; cnt++; }
  }
}

template <int N, int NCH>
__global__ void k_knn_merge(const float* __restrict__ v, const int* __restrict__ part,
                            int* __restrict__ nb) {
  int q = blockIdx.x * 64 + threadIdx.x;
  int b = blockIdx.y;
  const float* vb = v + (size_t)b * N * 3;
  float xq = vb[q * 3 + 0], yq = vb[q * 3 + 1], zq = vb[q * 3 + 2];
  float sqq = fmaf(xq, xq, fmaf(yq, yq, zq * zq));
  float kd[21]; int ki[21];
#pragma unroll
  for (int t = 0; t < 21; t++) { kd[t] = 3.4e38f; ki[t] = 0; }
  for (int ch = 0; ch < NCH; ch++) {
#pragma unroll 3
    for (int s = 0; s < 21; s++) {
      int idx = part[(((size_t)b * NCH + ch) * 21 + s) * N + q];
      float cx = vb[idx * 3 + 0], cy = vb[idx * 3 + 1], cz = vb[idx * 3 + 2];
      float cw = fmaf(cx, cx, fmaf(cy, cy, cz * cz));
      float dist = dist_fma(xq, yq, zq, sqq, cx, cy, cz, cw);
      if (dist < kd[20]) {
#pragma unroll
        for (int t = 20; t >= 1; t--) {
          bool shift = dist < kd[t - 1];
          float nk = shift ? kd[t - 1] : dist;
          int   ni = shift ? ki[t - 1] : idx;
          bool upd = dist < kd[t];
          if (upd) { kd[t] = nk; ki[t] = ni; }
        }
        if (dist < kd[0]) { kd[0] = dist; ki[0] = idx; }
      }
    }
  }
  int* nbq = nb + ((size_t)b * N + q) * NB_K;
#pragma unroll
  for (int t = 0; t < NB_K; t++) nbq[t] = ki[t + 1];
}

// ---------------------------------------------------------------------------
// conv_surface
// ---------------------------------------------------------------------------
__global__ void k_surface(const float* __restrict__ v, const int* __restrict__ nb,
                          const float* __restrict__ dirn, float* __restrict__ out) {
  int idx = blockIdx.x * 64 + threadIdx.x;  // b*4096+n
  int b = idx >> 12, n = idx & 4095;
  const float* vb = v + (size_t)b * 4096 * 3;
  float xq = vb[n * 3 + 0], yq = vb[n * 3 + 1], zq = vb[n * 3 + 2];
  float mx[32];
#pragma unroll
  for (int f = 0; f < 32; f++) mx[f] = 0.0f;
  for (int k = 0; k < NB_K; k++) {
    int j = nb[(size_t)idx * NB_K + k];
    float dx = vb[j * 3 + 0] - xq, dy = vb[j * 3 + 1] - yq, dz = vb[j * 3 + 2] - zq;
    float nr = sqrtf((dx * dx + dy * dy) + dz * dz);
    float inv = 1.0f / fmaxf(nr, 1e-12f);
    dx *= inv; dy *= inv; dz *= inv;
#pragma unroll
    for (int f = 0; f < 32; f++) {
      float th = dx * dirn[f] + dy * dirn[32 + f] + dz * dirn[64 + f];
      th = fmaxf(th, 0.0f);
      mx[f] = fmaxf(mx[f], th);
    }
  }
#pragma unroll
  for (int f = 0; f < 32; f++) out[(size_t)idx * 32 + f] = mx[f];
}

// ---------------------------------------------------------------------------
// Tiled fp32 GEMM: out[M,N] = A[M,K] @ W[K,N] (+bias). BM=BN=64, BK=16,
// 256 thr, 4x4 per thread. Requires M%64==0, N%64==0, K%16==0.
// Accumulation: acc=bias then k ascending (same order as reference matmul).
// ---------------------------------------------------------------------------
__global__ void k_gemm_tile(const float* __restrict__ A, const float* __restrict__ W,
                            const float* __restrict__ bias, float* __restrict__ out,
                            int M, int K, int N) {
  __shared__ float As[16][68];
  __shared__ float Bs[16][68];
  int m0 = blockIdx.y * 64, n0 = blockIdx.x * 64;
  int t = threadIdx.x;
  int tr = t >> 4, tc = t & 15;
  int am = t >> 2, ak4 = t & 3;       // A load: row am, k-quad ak4
  int bk = t >> 4, bn4 = t & 15;      // B load: k-row bk, n-quad bn4
  float acc[4][4];
#pragma unroll
  for (int j = 0; j < 4; j++) {
    float bv = bias ? bias[n0 + tc * 4 + j] : 0.0f;
#pragma unroll
    for (int i = 0; i < 4; i++) acc[i][j] = bv;
  }
  for (int k0 = 0; k0 < K; k0 += 16) {
    float4 av = *(const float4*)(A + (size_t)(m0 + am) * K + k0 + ak4 * 4);
    float4 wv = *(const float4*)(W + (size_t)(k0 + bk) * N + n0 + bn4 * 4);
    __syncthreads();
    As[ak4 * 4 + 0][am] = av.x;
    As[ak4 * 4 + 1][am] = av.y;
    As[ak4 * 4 + 2][am] = av.z;
    As[ak4 * 4 + 3][am] = av.w;
    *(float4*)(&Bs[bk][bn4 * 4]) = wv;
    __syncthreads();
#pragma unroll
    for (int kk = 0; kk < 16; kk++) {
      float a[4], b[4];
#pragma unroll
      for (int i = 0; i < 4; i++) a[i] = As[kk][tr * 4 + i];
#pragma unroll
      for (int j = 0; j < 4; j++) b[j] = Bs[kk][tc * 4 + j];
#pragma unroll
      for (int i = 0; i < 4; i++)
#pragma unroll
        for (int j = 0; j < 4; j++) acc[i][j] = fmaf(a[i], b[j], acc[i][j]);
    }
  }
#pragma unroll
  for (int i = 0; i < 4; i++)
    *(float4*)(out + (size_t)(m0 + tr * 4 + i) * N + n0 + tc * 4) =
        make_float4(acc[i][0], acc[i][1], acc[i][2], acc[i][3]);
}

// small-M GEMM (gating, M=8)
template <int K>
__global__ void k_gemm4(const float* __restrict__ A, const float* __restrict__ W,
                        const float* __restrict__ bias, float* __restrict__ out,
                        int R, int C) {
  int idx = blockIdx.x * 256 + threadIdx.x;
  int c4 = C >> 2;
  if (idx >= R * c4) return;
  int r = idx / c4, c = (idx - r * c4) << 2;
  const float* a = A + (size_t)r * K;
  float4 acc;
  if (bias) acc = *(const float4*)(bias + c);
  else acc = make_float4(0.f, 0.f, 0.f, 0.f);
#pragma unroll 8
  for (int k = 0; k < K; k++) {
    float av = a[k];
    float4 wv = *(const float4*)(W + (size_t)k * C + c);
    acc.x = fmaf(av, wv.x, acc.x);
    acc.y = fmaf(av, wv.y, acc.y);
    acc.z = fmaf(av, wv.z, acc.z);
    acc.w = fmaf(av, wv.w, acc.w);
  }
  *(float4*)(out + (size_t)r * C + c) = acc;
}

// ---------------------------------------------------------------------------
// conv_layer combine
// ---------------------------------------------------------------------------
template <int COUT, int CPT, bool RELU>
__global__ void k_combine(const float* __restrict__ v, const int* __restrict__ nb,
                          const float* __restrict__ fo, const float* __restrict__ dirn,
                          float* __restrict__ out, int N) {
  constexpr int THREADS = COUT / CPT;
  int bn = blockIdx.x;
  int b = bn / N, n = bn - b * N;
  __shared__ float ds[NB_K][3];
  __shared__ int nbs[NB_K];
  const float* vb = v + (size_t)b * N * 3;
  if (threadIdx.x < NB_K) {
    int j = nb[(size_t)bn * NB_K + threadIdx.x];
    nbs[threadIdx.x] = j;
    float xq = vb[n * 3 + 0], yq = vb[n * 3 + 1], zq = vb[n * 3 + 2];
    float dx = vb[j * 3 + 0] - xq, dy = vb[j * 3 + 1] - yq, dz = vb[j * 3 + 2] - zq;
    float nr = sqrtf((dx * dx + dy * dy) + dz * dz);
    float inv = 1.0f / fmaxf(nr, 1e-12f);
    ds[threadIdx.x][0] = dx * inv;
    ds[threadIdx.x][1] = dy * inv;
    ds[threadIdx.x][2] = dz * inv;
  }
  __syncthreads();
#pragma unroll
  for (int cc = 0; cc < CPT; cc++) {
    int c = threadIdx.x + cc * THREADS;
    float w0 = dirn[c], w1 = dirn[COUT + c], w2 = dirn[2 * COUT + c];
    float acc = -3.4e38f;
    for (int k = 0; k < NB_K; k++) {
      float th = ds[k][0] * w0 + ds[k][1] * w1 + ds[k][2] * w2;
      th = fmaxf(th, 0.0f);
      float fs = fo[((size_t)b * N + nbs[k]) * (2 * COUT) + COUT + c];
      acc = fmaxf(acc, th * fs);
    }
    float res = fo[(size_t)bn * (2 * COUT) + c] + acc;
    if (RELU) res = fmaxf(res, 0.0f);
    out[(size_t)bn * COUT + c] = res;
  }
}

// ---------------------------------------------------------------------------
// gather-max pooling over neighbors
// ---------------------------------------------------------------------------
template <int C>
__global__ void k_gathermax(const float* __restrict__ fm, const int* __restrict__ nb,
                            float* __restrict__ out, int N) {
  int bn = blockIdx.x;
  int b = bn / N;
  __shared__ int nbs[NB_K];
  if (threadIdx.x < NB_K) nbs[threadIdx.x] = nb[(size_t)bn * NB_K + threadIdx.x];
  __syncthreads();
  int c = threadIdx.x;
  float acc = -3.4e38f;
  for (int k = 0; k < NB_K; k++)
    acc = fmaxf(acc, fm[((size_t)b * N + nbs[k]) * C + c]);
  out[(size_t)bn * C + c] = acc;
}

// ---------------------------------------------------------------------------
// pool-index gather
// ---------------------------------------------------------------------------
__global__ void k_poolgather(const float* __restrict__ in, const int* __restrict__ pool,
                             float* __restrict__ out, int n_in, int n_out, int C) {
  int idx = blockIdx.x * 256 + threadIdx.x;
  if (idx >= 8 * n_out * C) return;
  int c = idx % C; int t = idx / C; int i = t % n_out; int b = t / n_out;
  out[idx] = in[((size_t)b * n_in + pool[i]) * C + c];
}

// ---------------------------------------------------------------------------
// GeM pooling (p==3 fast path; p is wave-uniform runtime scalar)
// ---------------------------------------------------------------------------
__global__ void k_gem(const float* __restrict__ fm4, const float* __restrict__ gp,
                      float* __restrict__ y) {
  int idx = blockIdx.x * 256 + threadIdx.x;  // b*1024+f
  int b = idx >> 10, f = idx & 1023;
  float p = gp[0];
  float s = 0.0f;
  if (p == 3.0f) {
    for (int n = 0; n < 256; n++) {
      float val = fmaxf(fm4[((size_t)b * 256 + n) * 1024 + f], 1e-6f);
      s += val * val * val;
    }
  } else {
    for (int n = 0; n < 256; n++) {
      float val = fmaxf(fm4[((size_t)b * 256 + n) * 1024 + f], 1e-6f);
      s += powf(val, p);
    }
  }
  y[idx] = powf(s * (1.0f / 256.0f), 1.0f / p);
}

// ---------------------------------------------------------------------------
// NetVLAD pieces
// ---------------------------------------------------------------------------
__global__ void k_bnstats(const float* __restrict__ x, int R, int C,
                          float* __restrict__ mean, float* __restrict__ rstd) {
  int c = blockIdx.x;
  __shared__ float red[256];
  float s = 0.0f;
  for (int r = threadIdx.x; r < R; r += 256) s += x[(size_t)r * C + c];
  red[threadIdx.x] = s; __syncthreads();
  for (int st = 128; st > 0; st >>= 1) {
    if (threadIdx.x < st) red[threadIdx.x] += red[threadIdx.x + st];
    __syncthreads();
  }
  float m = red[0] / (float)R;
  __syncthreads();
  float s2 = 0.0f;
  for (int r = threadIdx.x; r < R; r += 256) {
    float d = x[(size_t)r * C + c] - m; s2 += d * d;
  }
  red[threadIdx.x] = s2; __syncthreads();
  for (int st = 128; st > 0; st >>= 1) {
    if (threadIdx.x < st) red[threadIdx.x] += red[threadIdx.x + st];
    __syncthreads();
  }
  if (threadIdx.x == 0) {
    mean[c] = m;
    rstd[c] = 1.0f / sqrtf(red[0] / (float)R + BN_EPS);
  }
}

__global__ void k_softmax(const float* __restrict__ a0, const float* __restrict__ mean,
                          const float* __restrict__ rstd, const float* __restrict__ g,
                          const float* __restrict__ bb, float* __restrict__ act) {
  int r = blockIdx.x, c = threadIdx.x;
  float x = (a0[(size_t)r * 64 + c] - mean[c]) * rstd[c] * g[c] + bb[c];
  float mx = x;
  for (int off = 32; off > 0; off >>= 1) mx = fmaxf(mx, __shfl_xor(mx, off));
  float e = expf(x - mx);
  float sm = e;
  for (int off = 32; off > 0; off >>= 1) sm += __shfl_xor(sm, off);
  act[(size_t)r * 64 + c] = e / sm;
}

__global__ void k_colsum(const float* __restrict__ act, float* __restrict__ asum) {
  int b = blockIdx.x, k = threadIdx.x;
  float s = 0.0f;
  for (int m = 0; m < 256; m++) s += act[((size_t)b * 256 + m) * 64 + k];
  asum[b * 64 + k] = s;
}

// vlad[b,f,k] = sum_m xv[b,m,f]*act[b,m,k] - asum[b,k]*cw2[f,k]
// tiled: block (f-tile 64 x k 64), LDS-staged, 4x4 per thread
__global__ void k_vlad_tile(const float* __restrict__ act, const float* __restrict__ xv,
                            const float* __restrict__ asum, const float* __restrict__ cw2,
                            float* __restrict__ vlad) {
  __shared__ float Xs[64][68];   // [m][f]
  __shared__ float Ac[64][68];   // [m][k]
  int b = blockIdx.y, f0 = blockIdx.x * 64;
  int t = threadIdx.x, tr = t >> 4, tc = t & 15;
  float acc[4][4] = {};
  for (int m0 = 0; m0 < 256; m0 += 64) {
    __syncthreads();
#pragma unroll
    for (int r = 0; r < 4; r++) {
      int m = r * 16 + (t >> 4);
      *(float4*)(&Xs[m][(t & 15) * 4]) =
          *(const float4*)(xv + ((size_t)b * 256 + m0 + m) * 1024 + f0 + (t & 15) * 4);
      *(float4*)(&Ac[m][(t & 15) * 4]) =
          *(const float4*)(act + ((size_t)b * 256 + m0 + m) * 64 + (t & 15) * 4);
    }
    __syncthreads();
    for (int mm = 0; mm < 64; mm++) {
      float a[4], c[4];
#pragma unroll
      for (int i = 0; i < 4; i++) a[i] = Xs[mm][tr * 4 + i];
#pragma unroll
      for (int j = 0; j < 4; j++) c[j] = Ac[mm][tc * 4 + j];
#pragma unroll
      for (int i = 0; i < 4; i++)
#pragma unroll
        for (int j = 0; j < 4; j++) acc[i][j] = fmaf(a[i], c[j], acc[i][j]);
    }
  }
#pragma unroll
  for (int i = 0; i < 4; i++) {
    int f = f0 + tr * 4 + i;
#pragma unroll
    for (int j = 0; j < 4; j++) {
      int k = tc * 4 + j;
      vlad[((size_t)b * 1024 + f) * 64 + k] = acc[i][j] - asum[b * 64 + k] * cw2[f * 64 + k];
    }
  }
}

__global__ void k_norm1(const float* __restrict__ vlad, float* __restrict__ scale1) {
  int bk = blockIdx.x;  // b*64+k
  int b = bk >> 6, k = bk & 63;
  float s = 0.0f;
  for (int f = threadIdx.x; f < 1024; f += 64) {
    float val = vlad[((size_t)b * 1024 + f) * 64 + k];
    s += val * val;
  }
  for (int off = 32; off > 0; off >>= 1) s += __shfl_xor(s, off);
  if (threadIdx.x == 0) scale1[bk] = 1.0f / fmaxf(sqrtf(s), 1e-12f);
}

__global__ void k_norm2(const float* __restrict__ vlad, const float* __restrict__ scale1,
                        float* __restrict__ scale2) {
  int b = blockIdx.x;
  __shared__ float red[256];
  float s = 0.0f;
  for (int i = threadIdx.x; i < 65536; i += 256) {
    float val = vlad[(size_t)b * 65536 + i] * scale1[b * 64 + (i & 63)];
    s += val * val;
  }
  red[threadIdx.x] = s; __syncthreads();
  for (int st = 128; st > 0; st >>= 1) {
    if (threadIdx.x < st) red[threadIdx.x] += red[threadIdx.x + st];
    __syncthreads();
  }
  if (threadIdx.x == 0) scale2[b] = 1.0f / fmaxf(sqrtf(red[0]), 1e-12f);
}

__global__ void k_vscale(float* __restrict__ vlad, const float* __restrict__ scale1,
                         const float* __restrict__ scale2) {
  int idx = blockIdx.x * 256 + threadIdx.x;
  int b = idx >> 16; int r = idx & 65535;
  vlad[idx] = vlad[idx] * scale1[b * 64 + (r & 63)] * scale2[b];
}

__global__ void k_hidden_partial(const float* __restrict__ vlad, const float* __restrict__ hw,
                                 float* __restrict__ partial) {
  __shared__ float vs[8][512];
  int cg = blockIdx.x;   // 0..3
  int kb = blockIdx.y;   // 0..127
  int col = cg * 256 + threadIdx.x;
  int k0 = kb * 512;
  for (int i = threadIdx.x; i < 8 * 512; i += 256) {
    int b = i >> 9, k = i & 511;
    vs[b][k] = vlad[(size_t)b * 65536 + k0 + k];
  }
  __syncthreads();
  float acc[8] = {0, 0, 0, 0, 0, 0, 0, 0};
  for (int k = 0; k < 512; k++) {
    float w = hw[(size_t)(k0 + k) * 1024 + col];
#pragma unroll
    for (int b = 0; b < 8; b++) acc[b] += vs[b][k] * w;
  }
#pragma unroll
  for (int b = 0; b < 8; b++)
    partial[((size_t)kb * 8 + b) * 1024 + col] = acc[b];
}

__global__ void k_hidden_reduce(const float* __restrict__ partial, float* __restrict__ hid) {
  int idx = blockIdx.x * 256 + threadIdx.x;  // b*1024+c
  int b = idx >> 10, c = idx & 1023;
  float s = 0.0f;
  for (int kb = 0; kb < 128; kb++) s += partial[((size_t)kb * 8 + b) * 1024 + c];
  hid[idx] = s;
}

__global__ void k_bn8(const float* __restrict__ x, const float* __restrict__ g,
                      const float* __restrict__ bb, float* __restrict__ out) {
  int c = blockIdx.x * 256 + threadIdx.x;
  if (c >= 1024) return;
  float v[8]; float s = 0.0f;
#pragma unroll
  for (int b = 0; b < 8; b++) { v[b] = x[b * 1024 + c]; s += v[b]; }
  float m = s * 0.125f; float s2 = 0.0f;
#pragma unroll
  for (int b = 0; b < 8; b++) { float d = v[b] - m; s2 += d * d; }
  float rstd = 1.0f / sqrtf(s2 * 0.125f + BN_EPS);
#pragma unroll
  for (int b = 0; b < 8; b++) out[b * 1024 + c] = (v[b] - m) * rstd * g[c] + bb[c];
}

__global__ void k_gbn_out(const float* __restrict__ gat, const float* __restrict__ g,
                          const float* __restrict__ bb, const float* __restrict__ vladbn,
                          float* __restrict__ desc) {
  int c = blockIdx.x * 256 + threadIdx.x;
  if (c >= 1024) return;
  float v[8]; float s = 0.0f;
#pragma unroll
  for (int b = 0; b < 8; b++) { v[b] = gat[b * 1024 + c]; s += v[b]; }
  float m = s * 0.125f; float s2 = 0.0f;
#pragma unroll
  for (int b = 0; b < 8; b++) { float d = v[b] - m; s2 += d * d; }
  float rstd = 1.0f / sqrtf(s2 * 0.125f + BN_EPS);
#pragma unroll
  for (int b = 0; b < 8; b++) {
    float x = (v[b] - m) * rstd * g[c] + bb[c];
    float gate = 1.0f / (1.0f + expf(-x));
    desc[b * 1024 + c] = vladbn[b * 1024 + c] * gate;
  }
}

// ---------------------------------------------------------------------------
// launch
// ---------------------------------------------------------------------------
extern "C" void kernel_launch(void* const* d_in, const int* in_sizes, int n_in,
                              void* d_out, int out_size, void* d_ws, size_t ws_size,
                              hipStream_t stream) {
  (void)in_sizes; (void)n_in; (void)out_size; (void)ws_size;
  const float* x    = (const float*)d_in[0];
  const float* dir0 = (const float*)d_in[1];
  const float* W1   = (const float*)d_in[2];
  const float* b1   = (const float*)d_in[3];
  const float* dir1 = (const float*)d_in[4];
  const float* W2   = (const float*)d_in[5];
  const float* b2   = (const float*)d_in[6];
  const float* dir2 = (const float*)d_in[7];
  const float* W3   = (const float*)d_in[8];
  const float* b3   = (const float*)d_in[9];
  const float* dir3 = (const float*)d_in[10];
  const float* W4   = (const float*)d_in[11];
  const float* b4   = (const float*)d_in[12];
  const float* dir4 = (const float*)d_in[13];
  const float* gemp = (const float*)d_in[14];
  const float* cw   = (const float*)d_in[15];
  const float* cw2  = (const float*)d_in[16];
  const float* hw   = (const float*)d_in[17];
  const float* bn1g = (const float*)d_in[18];
  const float* bn1b = (const float*)d_in[19];
  const float* bn2g = (const float*)d_in[20];
  const float* bn2b = (const float*)d_in[21];
  const float* gw   = (const float*)d_in[22];
  const float* gbng = (const float*)d_in[23];
  const float* gbnb = (const float*)d_in[24];
  float* out = (float*)d_out;
  char* ws = (char*)d_ws;

  float* F_DIRN0 = (float*)(ws + OFF_DIRN0);
  float* F_DIRN1 = (float*)(ws + OFF_DIRN1);
  float* F_DIRN2 = (float*)(ws + OFF_DIRN2);
  float* F_DIRN3 = (float*)(ws + OFF_DIRN3);
  float* F_DIRN4 = (float*)(ws + OFF_DIRN4);
  int*   I_POOL1 = (int*)(ws + OFF_POOL1);
  int*   I_POOL2 = (int*)(ws + OFF_POOL2);
  int*   I_NB    = (int*)(ws + OFF_NB);
  int*   I_KPART = (int*)(ws + OFF_KPART);
  unsigned short* U_KSURV = (unsigned short*)(ws + OFF_KSURV);
  int*   I_KCNT  = (int*)(ws + OFF_KCNT);
  float* F_KT0   = (float*)(ws + OFF_KT0);
  float* F_V2    = (float*)(ws + OFF_V2);
  float* F_V3    = (float*)(ws + OFF_V3);
  float* F_X1    = (float*)(ws + OFF_X1);
  float* F_X2    = (float*)(ws + OFF_X2);
  float* F_X3    = (float*)(ws + OFF_X3);
  float* F_X4    = (float*)(ws + OFF_X4);

  hipMemcpyAsync(I_POOL1, g_pools.p1, sizeof(g_pools.p1), hipMemcpyHostToDevice, stream);
  hipMemcpyAsync(I_POOL2, g_pools.p2, sizeof(g_pools.p2), hipMemcpyHostToDevice, stream);

  k_dirnorm<<<6, 256, 0, stream>>>(dir0, dir1, dir2, dir3, dir4,
                                   F_DIRN0, F_DIRN1, F_DIRN2, F_DIRN3, F_DIRN4);

  // ---- level 0: 4096 pts (sample -> filter -> merge) ----
  k_knn_sample<4096, 512><<<dim3(64, 8), 64, 0, stream>>>(x, F_KT0);
  k_knn_filter<4096, 512, 8, 64><<<dim3(64, 8, 8), 64, 0, stream>>>(x, F_KT0, U_KSURV, I_KCNT);
  k_knn_merge2<4096, 8, 64><<<dim3(64, 8), 64, 0, stream>>>(x, U_KSURV, I_KCNT, I_NB);
  k_surface<<<512, 64, 0, stream>>>(x, I_NB, F_DIRN0, F_X3);
  k_gemm_tile<<<dim3(2, 512), 256, 0, stream>>>(F_X3, W1, b1, F_X1, 32768, 32, 128);
  k_combine<64, 1, true><<<32768, 64, 0, stream>>>(x, I_NB, F_X1, F_DIRN1, F_X4, 4096);
  k_gathermax<64><<<32768, 64, 0, stream>>>(F_X4, I_NB, F_X2, 4096);
  k_poolgather<<<(8 * 1024 * 3 + 255) / 256, 256, 0, stream>>>(x, I_POOL1, F_V2, 4096, 1024, 3);
  k_poolgather<<<(8 * 1024 * 64 + 255) / 256, 256, 0, stream>>>(F_X2, I_POOL1, F_X3, 4096, 1024, 64);

  // ---- level 1: 1024 pts ----
  k_knn_part<1024, 128, 8><<<dim3(16, 8, 8), 64, 0, stream>>>(F_V2, I_KPART);
  k_knn_merge<1024, 8><<<dim3(16, 8), 64, 0, stream>>>(F_V2, I_KPART, I_NB);
  k_gemm_tile<<<dim3(4, 128), 256, 0, stream>>>(F_X3, W2, b2, F_X4, 8192, 64, 256);
  k_combine<128, 1, true><<<8192, 128, 0, stream>>>(F_V2, I_NB, F_X4, F_DIRN2, F_X1, 1024);
  k_gemm_tile<<<dim3(8, 128), 256, 0, stream>>>(F_X1, W3, b3, F_X2, 8192, 128, 512);
  k_combine<256, 1, true><<<8192, 256, 0, stream>>>(F_V2, I_NB, F_X2, F_DIRN3, F_X4, 1024);
  k_gathermax<256><<<8192, 256, 0, stream>>>(F_X4, I_NB, F_X1, 1024);
  k_poolgather<<<(8 * 256 * 3 + 255) / 256, 256, 0, stream>>>(F_V2, I_POOL2, F_V3, 1024, 256, 3);
  k_poolgather<<<(8 * 256 * 256 + 255) / 256, 256, 0, stream>>>(F_X1, I_POOL2, F_X3, 1024, 256, 256);

  // ---- level 2: 256 pts ----
  k_knn_part<256, 64, 4><<<dim3(4, 4, 8), 64, 0, stream>>>(F_V3, I_KPART);
  k_knn_merge<256, 4><<<dim3(4, 8), 64, 0, stream>>>(F_V3, I_KPART, I_NB);
  k_gemm_tile<<<dim3(32, 32), 256, 0, stream>>>(F_X3, W4, b4, F_X2, 2048, 256, 2048);
  k_combine<1024, 4, false><<<2048, 256, 0, stream>>>(F_V3, I_NB, F_X2, F_DIRN4, F_X4, 256);

  // ---- GeM head -> out[0:8192] ----
  k_gem<<<32, 256, 0, stream>>>(F_X4, gemp, out);

  // ---- NetVLAD head -> out[8192:16384] ----
  float* F_ACT0 = (float*)(ws + OFF_ACT0);
  float* F_ACT  = (float*)(ws + OFF_ACT);
  float* F_VLAD = (float*)(ws + OFF_VLAD);
  float* F_PART = (float*)(ws + OFF_PART);
  float* F_BN1M = (float*)(ws + OFF_BN1M);
  float* F_BN1R = (float*)(ws + OFF_BN1R);
  float* F_ASUM = (float*)(ws + OFF_ASUM);
  float* F_SC1  = (float*)(ws + OFF_SCALE1);
  float* F_SC2  = (float*)(ws + OFF_SCALE2);
  float* F_HID  = (float*)(ws + OFF_HID);
  float* F_VBN  = (float*)(ws + OFF_VLADBN);
  float* F_GAT  = (float*)(ws + OFF_GAT);

  k_gemm_tile<<<dim3(1, 32), 256, 0, stream>>>(F_X4, cw, nullptr, F_ACT0, 2048, 1024, 64);
  k_bnstats<<<64, 256, 0, stream>>>(F_ACT0, 2048, 64, F_BN1M, F_BN1R);
  k_softmax<<<2048, 64, 0, stream>>>(F_ACT0, F_BN1M, F_BN1R, bn1g, bn1b, F_ACT);
  k_colsum<<<8, 64, 0, stream>>>(F_ACT, F_ASUM);
  k_vlad_tile<<<dim3(16, 8), 256, 0, stream>>>(F_ACT, F_X4, F_ASUM, cw2, F_VLAD);
  k_norm1<<<512, 64, 0, stream>>>(F_VLAD, F_SC1);
  k_norm2<<<8, 256, 0, stream>>>(F_VLAD, F_SC1, F_SC2);
  k_vscale<<<(8 * 65536) / 256, 256, 0, stream>>>(F_VLAD, F_SC1, F_SC2);
  k_hidden_partial<<<dim3(4, 128), 256, 0, stream>>>(F_VLAD, hw, F_PART);
  k_hidden_reduce<<<32, 256, 0, stream>>>(F_PART, F_HID);
  k_bn8<<<4, 256, 0, stream>>>(F_HID, bn2g, bn2b, F_VBN);
  k_gemm4<1024><<<(8 * 256 + 255) / 256, 256, 0, stream>>>(F_VBN, gw, nullptr, F_GAT, 8, 1024);
  k_gbn_out<<<4, 256, 0, stream>>>(F_GAT, gbng, gbnb, F_VBN, out + 8192);
}